// Round 1
// baseline (190.198 us; speedup 1.0000x reference)
//
#include <hip/hip_runtime.h>
#include <math.h>

#define N_AA 21
#define NATOM 15
#define DF 128
#define H1DIM 256
#define OFF_COORD 128
#define OFF_DIH 1073
#define OFF_CHAIN 1112
#define T 32
#define STR (T + 4)   // LDS row stride: keeps float4 (16B) alignment for r0 % 4 == 0

__constant__ float c_freq[6] = {1.0f, 2.0f, 3.0f, 1.0f, 0.5f, 1.0f / 3.0f};

#define FMA4(A, s, w)            \
  A.x = fmaf((s), (w).x, A.x);   \
  A.y = fmaf((s), (w).y, A.y);   \
  A.z = fmaf((s), (w).z, A.z);   \
  A.w = fmaf((s), (w).w, A.w);

// tabAA[t][i] = sum_k aa_emb[t][k] * W1[k][i]
// tabCH[c][i] = b1[i] + sum_k chain_emb[c][k] * W1[OFF_CHAIN+k][i]
__global__ __launch_bounds__(256) void precompute_tables(
    const float* __restrict__ aa_emb, const float* __restrict__ chain_emb,
    const float* __restrict__ W1, const float* __restrict__ b1,
    float* __restrict__ tabAA, float* __restrict__ tabCH) {
  const int i = threadIdx.x;
  const int b = blockIdx.x;
  if (b < N_AA) {
    const float* e = aa_emb + b * DF;
    float acc = 0.f;
#pragma unroll 8
    for (int k = 0; k < DF; ++k) acc = fmaf(e[k], W1[k * H1DIM + i], acc);
    tabAA[b * H1DIM + i] = acc;
  } else {
    const int c = b - N_AA;
    const float* e = chain_emb + c * DF;
    float acc = b1[i];
#pragma unroll 8
    for (int k = 0; k < DF; ++k)
      acc = fmaf(e[k], W1[(OFF_CHAIN + k) * H1DIM + i], acc);
    tabCH[c * H1DIM + i] = acc;
  }
}

__global__ __launch_bounds__(512) void residue_embed_kernel(
    const int* __restrict__ seq_idx, const float* __restrict__ xyz,
    const float* __restrict__ orient, const float* __restrict__ dihedrals,
    const int* __restrict__ chain_idx, const float* __restrict__ amask,
    const float* __restrict__ W1, const float* __restrict__ W2,
    const float* __restrict__ b2, const float* __restrict__ W3,
    const float* __restrict__ b3, const float* __restrict__ W4,
    const float* __restrict__ b4, const float* __restrict__ tabAA,
    const float* __restrict__ tabCH, float* __restrict__ out, int n_res) {
  __shared__ float s_coordT[45][STR];   // [k][r] xyz_local, transposed
  __shared__ float s_dihT[39][STR];     // [k][r] dihedral enc, transposed
  __shared__ float s_h1t[H1DIM][STR];   // h1 transposed; rows 0..127 reused as h3
  __shared__ float s_h2t[DF][STR];      // h2 transposed
  __shared__ int s_t[T];
  __shared__ int s_c[T];

  const int tid = threadIdx.x;
  const int base = blockIdx.x * T;

  // ---- phase 0: indices, local coords, dihedral encoding ----
  if (tid < T) {
    s_t[tid] = seq_idx[base + tid];
    s_c[tid] = chain_idx[base + tid];
  }
  for (int idx = tid; idx < T * 45; idx += 512) {
    const int r = idx / 45, k = idx % 45;
    const int a = k / 3, i = k % 3;
    const int g = base + r;
    const float* X = xyz + g * 45;
    const float* R = orient + g * 9;
    const float m = amask[g * NATOM + a];
    float v = 0.f;
#pragma unroll
    for (int j = 0; j < 3; ++j)
      v = fmaf(R[j * 3 + i], X[a * 3 + j] - X[3 + j], v);  // CA = atom 1
    s_coordT[k][r] = v * m;
  }
  for (int idx = tid; idx < T * 39; idx += 512) {
    const int r = idx / 39, k = idx % 39;
    const int d = k / 13, m = k % 13;
    const float x = dihedrals[(base + r) * 3 + d];
    float v;
    if (m == 0)
      v = x;
    else if (m <= 6)
      v = sinf(c_freq[m - 1] * x);
    else
      v = cosf(c_freq[m - 7] * x);
    s_dihT[k][r] = v;
  }
  __syncthreads();

  // ---- layer 1: h1[T][256] = relu(feats @ W1 + b1), sparse-gathered ----
  {
    const int i0 = (tid & 63) * 4;  // 64 col groups cover 256 cols
    const int r0 = (tid >> 6) * 4;  // 8 residue groups of 4
    float4 acc[4];
#pragma unroll
    for (int rr = 0; rr < 4; ++rr) {
      const int t = s_t[r0 + rr], c = s_c[r0 + rr];
      const float4 a = *(const float4*)(tabAA + t * H1DIM + i0);
      const float4 b = *(const float4*)(tabCH + c * H1DIM + i0);
      acc[rr].x = a.x + b.x; acc[rr].y = a.y + b.y;
      acc[rr].z = a.z + b.z; acc[rr].w = a.w + b.w;
    }
    // dihedral rows (same 39 W1 rows for all residues)
#pragma unroll 3
    for (int k = 0; k < 39; ++k) {
      const float4 w = *(const float4*)(W1 + (OFF_DIH + k) * H1DIM + i0);
      const float4 av = *(const float4*)(&s_dihT[k][r0]);
      FMA4(acc[0], av.x, w);
      FMA4(acc[1], av.y, w);
      FMA4(acc[2], av.z, w);
      FMA4(acc[3], av.w, w);
    }
    // coord rows (45 rows, per-residue type slice of W1)
#pragma unroll
    for (int rr = 0; rr < 4; ++rr) {
      const int t = s_t[r0 + rr];
      const float* wp = W1 + (OFF_COORD + t * 45) * H1DIM + i0;
#pragma unroll 5
      for (int k = 0; k < 45; ++k) {
        const float4 w = *(const float4*)(wp + k * H1DIM);
        const float a = s_coordT[k][r0 + rr];
        FMA4(acc[rr], a, w);
      }
    }
#pragma unroll
    for (int rr = 0; rr < 4; ++rr) {
      s_h1t[i0 + 0][r0 + rr] = fmaxf(acc[rr].x, 0.f);
      s_h1t[i0 + 1][r0 + rr] = fmaxf(acc[rr].y, 0.f);
      s_h1t[i0 + 2][r0 + rr] = fmaxf(acc[rr].z, 0.f);
      s_h1t[i0 + 3][r0 + rr] = fmaxf(acc[rr].w, 0.f);
    }
  }
  __syncthreads();

  const int j0 = (tid & 31) * 4;  // 32 col groups cover 128 cols
  const int r0 = (tid >> 5) * 2;  // 16 residue groups of 2

  // ---- layer 2: h2[T][128] = relu(h1 @ W2 + b2) ----
  {
    const float4 bb = *(const float4*)(b2 + j0);
    float4 acc0 = bb, acc1 = bb;
#pragma unroll 4
    for (int k = 0; k < H1DIM; ++k) {
      const float4 w = *(const float4*)(W2 + k * DF + j0);
      const float2 a = *(const float2*)(&s_h1t[k][r0]);
      FMA4(acc0, a.x, w);
      FMA4(acc1, a.y, w);
    }
    __syncthreads();  // h1 consumed by everyone before h3 overwrites it later
    s_h2t[j0 + 0][r0] = fmaxf(acc0.x, 0.f); s_h2t[j0 + 0][r0 + 1] = fmaxf(acc1.x, 0.f);
    s_h2t[j0 + 1][r0] = fmaxf(acc0.y, 0.f); s_h2t[j0 + 1][r0 + 1] = fmaxf(acc1.y, 0.f);
    s_h2t[j0 + 2][r0] = fmaxf(acc0.z, 0.f); s_h2t[j0 + 2][r0 + 1] = fmaxf(acc1.z, 0.f);
    s_h2t[j0 + 3][r0] = fmaxf(acc0.w, 0.f); s_h2t[j0 + 3][r0 + 1] = fmaxf(acc1.w, 0.f);
  }
  __syncthreads();

  // ---- layer 3: h3[T][128] = relu(h2 @ W3 + b3) -> stored into s_h1t rows 0..127 ----
  {
    const float4 bb = *(const float4*)(b3 + j0);
    float4 acc0 = bb, acc1 = bb;
#pragma unroll 4
    for (int k = 0; k < DF; ++k) {
      const float4 w = *(const float4*)(W3 + k * DF + j0);
      const float2 a = *(const float2*)(&s_h2t[k][r0]);
      FMA4(acc0, a.x, w);
      FMA4(acc1, a.y, w);
    }
    s_h1t[j0 + 0][r0] = fmaxf(acc0.x, 0.f); s_h1t[j0 + 0][r0 + 1] = fmaxf(acc1.x, 0.f);
    s_h1t[j0 + 1][r0] = fmaxf(acc0.y, 0.f); s_h1t[j0 + 1][r0 + 1] = fmaxf(acc1.y, 0.f);
    s_h1t[j0 + 2][r0] = fmaxf(acc0.z, 0.f); s_h1t[j0 + 2][r0 + 1] = fmaxf(acc1.z, 0.f);
    s_h1t[j0 + 3][r0] = fmaxf(acc0.w, 0.f); s_h1t[j0 + 3][r0 + 1] = fmaxf(acc1.w, 0.f);
  }
  __syncthreads();

  // ---- layer 4: out[T][128] = h3 @ W4 + b4 (no relu) ----
  {
    const float4 bb = *(const float4*)(b4 + j0);
    float4 acc0 = bb, acc1 = bb;
#pragma unroll 4
    for (int k = 0; k < DF; ++k) {
      const float4 w = *(const float4*)(W4 + k * DF + j0);
      const float2 a = *(const float2*)(&s_h1t[k][r0]);
      FMA4(acc0, a.x, w);
      FMA4(acc1, a.y, w);
    }
    *(float4*)(out + (size_t)(base + r0) * DF + j0) = acc0;
    *(float4*)(out + (size_t)(base + r0 + 1) * DF + j0) = acc1;
  }
}

extern "C" void kernel_launch(void* const* d_in, const int* in_sizes, int n_in,
                              void* d_out, int out_size, void* d_ws, size_t ws_size,
                              hipStream_t stream) {
  const int* seq = (const int*)d_in[0];
  const float* xyz = (const float*)d_in[1];
  const float* orient = (const float*)d_in[2];
  const float* dihedrals = (const float*)d_in[3];
  const int* chain = (const int*)d_in[4];
  const float* amask = (const float*)d_in[5];
  const float* aa_emb = (const float*)d_in[6];
  const float* chain_emb = (const float*)d_in[7];
  const float* W1 = (const float*)d_in[8];
  const float* b1 = (const float*)d_in[9];
  const float* W2 = (const float*)d_in[10];
  const float* b2 = (const float*)d_in[11];
  const float* W3 = (const float*)d_in[12];
  const float* b3 = (const float*)d_in[13];
  const float* W4 = (const float*)d_in[14];
  const float* b4 = (const float*)d_in[15];
  float* out = (float*)d_out;
  const int n_res = in_sizes[0];  // B*L = 32768

  float* tabAA = (float*)d_ws;                 // 21*256 floats
  float* tabCH = tabAA + N_AA * H1DIM;         // 10*256 floats

  hipLaunchKernelGGL(precompute_tables, dim3(N_AA + 10), dim3(256), 0, stream,
                     aa_emb, chain_emb, W1, b1, tabAA, tabCH);

  const int nblk = n_res / T;
  hipLaunchKernelGGL(residue_embed_kernel, dim3(nblk), dim3(512), 0, stream,
                     seq, xyz, orient, dihedrals, chain, amask, W1, W2, b2, W3,
                     b3, W4, b4, tabAA, tabCH, out, n_res);
}

// Round 3
// 186.283 us; speedup vs baseline: 1.0210x; 1.0210x over previous
//
#include <hip/hip_runtime.h>
#include <math.h>

#define N_AA 21
#define NATOM 15
#define DF 128
#define H1DIM 256
#define OFF_COORD 128
#define OFF_DIH 1073
#define OFF_CHAIN 1112
#define T 32
#define H1STR 260   // row stride for s_h1 (float4-aligned, 256+4)
#define BUFSTR 132  // row stride for s_buf2 (h2 / coord+dih union)
#define DIH0 46     // dihedral enc starts at col 46 inside s_buf2 row

__constant__ float c_freq[6] = {1.0f, 2.0f, 3.0f, 1.0f, 0.5f, 1.0f / 3.0f};

// NOTE: uppercase macro params — lowercase `w` collided with the .w member.
#define FMA4(A, S, W)            \
  A.x = fmaf((S), (W).x, A.x);   \
  A.y = fmaf((S), (W).y, A.y);   \
  A.z = fmaf((S), (W).z, A.z);   \
  A.w = fmaf((S), (W).w, A.w);

// tabAA[t][i] = sum_k aa_emb[t][k] * W1[k][i]
// tabCH[c][i] = b1[i] + sum_k chain_emb[c][k] * W1[OFF_CHAIN+k][i]
__global__ __launch_bounds__(256) void precompute_tables(
    const float* __restrict__ aa_emb, const float* __restrict__ chain_emb,
    const float* __restrict__ W1, const float* __restrict__ b1,
    float* __restrict__ tabAA, float* __restrict__ tabCH) {
  const int i = threadIdx.x;
  const int b = blockIdx.x;
  if (b < N_AA) {
    const float* e = aa_emb + b * DF;
    float acc = 0.f;
#pragma unroll 8
    for (int k = 0; k < DF; ++k) acc = fmaf(e[k], W1[k * H1DIM + i], acc);
    tabAA[b * H1DIM + i] = acc;
  } else {
    const int c = b - N_AA;
    const float* e = chain_emb + c * DF;
    float acc = b1[i];
#pragma unroll 8
    for (int k = 0; k < DF; ++k)
      acc = fmaf(e[k], W1[(OFF_CHAIN + k) * H1DIM + i], acc);
    tabCH[c * H1DIM + i] = acc;
  }
}

__global__ __launch_bounds__(512, 6) void residue_embed_kernel(
    const int* __restrict__ seq_idx, const float* __restrict__ xyz,
    const float* __restrict__ orient, const float* __restrict__ dihedrals,
    const int* __restrict__ chain_idx, const float* __restrict__ amask,
    const float* __restrict__ W1, const float* __restrict__ W2,
    const float* __restrict__ b2, const float* __restrict__ W3,
    const float* __restrict__ b3, const float* __restrict__ W4,
    const float* __restrict__ b4, const float* __restrict__ tabAA,
    const float* __restrict__ tabCH, float* __restrict__ out, int n_res) {
  // Row-major activations: writes are contiguous float4 per row (conflict-
  // free), reads are wave-broadcast (same address across lanes -> free).
  __shared__ float s_h1[T][H1STR];    // h1 [r][0..255]; later h3 in cols 0..127
  __shared__ float s_buf2[T][BUFSTR]; // phase0: coord[r][0..44], dih[r][46..84]; later h2[r][0..127]
  __shared__ int s_t[T];
  __shared__ int s_c[T];

  const int tid = threadIdx.x;
  const int base = blockIdx.x * T;

  // ---- phase 0: indices, local coords, dihedral encoding ----
  if (tid < T) {
    s_t[tid] = seq_idx[base + tid];
    s_c[tid] = chain_idx[base + tid];
  }
  for (int idx = tid; idx < T * 45; idx += 512) {
    const int r = idx / 45, k = idx % 45;
    const int a = k / 3, i = k % 3;
    const int g = base + r;
    const float* X = xyz + g * 45;
    const float* R = orient + g * 9;
    const float m = amask[g * NATOM + a];
    float v = 0.f;
#pragma unroll
    for (int j = 0; j < 3; ++j)
      v = fmaf(R[j * 3 + i], X[a * 3 + j] - X[3 + j], v);  // CA = atom 1
    s_buf2[r][k] = v * m;
  }
  for (int idx = tid; idx < T * 39; idx += 512) {
    const int r = idx / 39, k = idx % 39;
    const int d = k / 13, m = k % 13;
    const float x = dihedrals[(base + r) * 3 + d];
    float v;
    if (m == 0)
      v = x;
    else if (m <= 6)
      v = sinf(c_freq[m - 1] * x);
    else
      v = cosf(c_freq[m - 7] * x);
    s_buf2[r][DIH0 + k] = v;
  }
  __syncthreads();

  // ---- layer 1: h1[T][256] = relu(feats @ W1 + b1), sparse-gathered ----
  {
    const int i0 = (tid & 63) * 4;  // 64 col groups cover 256 cols
    const int r0 = (tid >> 6) * 4;  // 8 residue groups of 4
    float4 acc[4];
#pragma unroll
    for (int rr = 0; rr < 4; ++rr) {
      const int t = s_t[r0 + rr], c = s_c[r0 + rr];
      const float4 a = *(const float4*)(tabAA + t * H1DIM + i0);
      const float4 b = *(const float4*)(tabCH + c * H1DIM + i0);
      acc[rr].x = a.x + b.x; acc[rr].y = a.y + b.y;
      acc[rr].z = a.z + b.z; acc[rr].w = a.w + b.w;
    }
    // dihedral rows (same 39 W1 rows for all residues)
#pragma unroll 3
    for (int k = 0; k < 39; ++k) {
      const float4 wv = *(const float4*)(W1 + (OFF_DIH + k) * H1DIM + i0);
#pragma unroll
      for (int rr = 0; rr < 4; ++rr) {
        FMA4(acc[rr], s_buf2[r0 + rr][DIH0 + k], wv);
      }
    }
    // coord rows: 4 independent per-residue weight streams, 2 k per step
    const float* wp[4];
#pragma unroll
    for (int rr = 0; rr < 4; ++rr)
      wp[rr] = W1 + (OFF_COORD + s_t[r0 + rr] * 45) * H1DIM + i0;
    for (int k = 0; k < 44; k += 2) {
#pragma unroll
      for (int rr = 0; rr < 4; ++rr) {
        const float2 a2 = *(const float2*)(&s_buf2[r0 + rr][k]);
        const float4 w0 = *(const float4*)(wp[rr] + k * H1DIM);
        const float4 w1 = *(const float4*)(wp[rr] + (k + 1) * H1DIM);
        FMA4(acc[rr], a2.x, w0);
        FMA4(acc[rr], a2.y, w1);
      }
    }
#pragma unroll
    for (int rr = 0; rr < 4; ++rr) {  // tail k = 44
      const float4 wv = *(const float4*)(wp[rr] + 44 * H1DIM);
      FMA4(acc[rr], s_buf2[r0 + rr][44], wv);
    }
#pragma unroll
    for (int rr = 0; rr < 4; ++rr) {
      float4 v;
      v.x = fmaxf(acc[rr].x, 0.f);
      v.y = fmaxf(acc[rr].y, 0.f);
      v.z = fmaxf(acc[rr].z, 0.f);
      v.w = fmaxf(acc[rr].w, 0.f);
      *(float4*)(&s_h1[r0 + rr][i0]) = v;
    }
  }
  __syncthreads();

  const int j0 = (tid & 31) * 4;  // 32 col groups cover 128 cols
  const int r2 = (tid >> 5) * 2;  // 16 residue groups of 2

  // ---- layer 2: h2[T][128] = relu(h1 @ W2 + b2) ----
  {
    const float4 bb = *(const float4*)(b2 + j0);
    float4 acc0 = bb, acc1 = bb;
#pragma unroll 2
    for (int k = 0; k < H1DIM; k += 4) {
      const float4 a0 = *(const float4*)(&s_h1[r2][k]);
      const float4 a1 = *(const float4*)(&s_h1[r2 + 1][k]);
      const float4 w0 = *(const float4*)(W2 + (k + 0) * DF + j0);
      const float4 w1 = *(const float4*)(W2 + (k + 1) * DF + j0);
      const float4 w2 = *(const float4*)(W2 + (k + 2) * DF + j0);
      const float4 w3 = *(const float4*)(W2 + (k + 3) * DF + j0);
      FMA4(acc0, a0.x, w0); FMA4(acc1, a1.x, w0);
      FMA4(acc0, a0.y, w1); FMA4(acc1, a1.y, w1);
      FMA4(acc0, a0.z, w2); FMA4(acc1, a1.z, w2);
      FMA4(acc0, a0.w, w3); FMA4(acc1, a1.w, w3);
    }
    float4 v0, v1;
    v0.x = fmaxf(acc0.x, 0.f); v0.y = fmaxf(acc0.y, 0.f);
    v0.z = fmaxf(acc0.z, 0.f); v0.w = fmaxf(acc0.w, 0.f);
    v1.x = fmaxf(acc1.x, 0.f); v1.y = fmaxf(acc1.y, 0.f);
    v1.z = fmaxf(acc1.z, 0.f); v1.w = fmaxf(acc1.w, 0.f);
    *(float4*)(&s_buf2[r2][j0]) = v0;      // h2 overwrites coord/dih (consumed)
    *(float4*)(&s_buf2[r2 + 1][j0]) = v1;
  }
  __syncthreads();

  // ---- layer 3: h3 = relu(h2 @ W3 + b3) -> s_h1 cols 0..127 ----
  {
    const float4 bb = *(const float4*)(b3 + j0);
    float4 acc0 = bb, acc1 = bb;
#pragma unroll 2
    for (int k = 0; k < DF; k += 4) {
      const float4 a0 = *(const float4*)(&s_buf2[r2][k]);
      const float4 a1 = *(const float4*)(&s_buf2[r2 + 1][k]);
      const float4 w0 = *(const float4*)(W3 + (k + 0) * DF + j0);
      const float4 w1 = *(const float4*)(W3 + (k + 1) * DF + j0);
      const float4 w2 = *(const float4*)(W3 + (k + 2) * DF + j0);
      const float4 w3 = *(const float4*)(W3 + (k + 3) * DF + j0);
      FMA4(acc0, a0.x, w0); FMA4(acc1, a1.x, w0);
      FMA4(acc0, a0.y, w1); FMA4(acc1, a1.y, w1);
      FMA4(acc0, a0.z, w2); FMA4(acc1, a1.z, w2);
      FMA4(acc0, a0.w, w3); FMA4(acc1, a1.w, w3);
    }
    __syncthreads();  // everyone done reading h1 before overwrite
    float4 v0, v1;
    v0.x = fmaxf(acc0.x, 0.f); v0.y = fmaxf(acc0.y, 0.f);
    v0.z = fmaxf(acc0.z, 0.f); v0.w = fmaxf(acc0.w, 0.f);
    v1.x = fmaxf(acc1.x, 0.f); v1.y = fmaxf(acc1.y, 0.f);
    v1.z = fmaxf(acc1.z, 0.f); v1.w = fmaxf(acc1.w, 0.f);
    *(float4*)(&s_h1[r2][j0]) = v0;
    *(float4*)(&s_h1[r2 + 1][j0]) = v1;
  }
  __syncthreads();

  // ---- layer 4: out = h3 @ W4 + b4 (no relu) ----
  {
    const float4 bb = *(const float4*)(b4 + j0);
    float4 acc0 = bb, acc1 = bb;
#pragma unroll 2
    for (int k = 0; k < DF; k += 4) {
      const float4 a0 = *(const float4*)(&s_h1[r2][k]);
      const float4 a1 = *(const float4*)(&s_h1[r2 + 1][k]);
      const float4 w0 = *(const float4*)(W4 + (k + 0) * DF + j0);
      const float4 w1 = *(const float4*)(W4 + (k + 1) * DF + j0);
      const float4 w2 = *(const float4*)(W4 + (k + 2) * DF + j0);
      const float4 w3 = *(const float4*)(W4 + (k + 3) * DF + j0);
      FMA4(acc0, a0.x, w0); FMA4(acc1, a1.x, w0);
      FMA4(acc0, a0.y, w1); FMA4(acc1, a1.y, w1);
      FMA4(acc0, a0.z, w2); FMA4(acc1, a1.z, w2);
      FMA4(acc0, a0.w, w3); FMA4(acc1, a1.w, w3);
    }
    *(float4*)(out + (size_t)(base + r2) * DF + j0) = acc0;
    *(float4*)(out + (size_t)(base + r2 + 1) * DF + j0) = acc1;
  }
}

extern "C" void kernel_launch(void* const* d_in, const int* in_sizes, int n_in,
                              void* d_out, int out_size, void* d_ws, size_t ws_size,
                              hipStream_t stream) {
  const int* seq = (const int*)d_in[0];
  const float* xyz = (const float*)d_in[1];
  const float* orient = (const float*)d_in[2];
  const float* dihedrals = (const float*)d_in[3];
  const int* chain = (const int*)d_in[4];
  const float* amask = (const float*)d_in[5];
  const float* aa_emb = (const float*)d_in[6];
  const float* chain_emb = (const float*)d_in[7];
  const float* W1 = (const float*)d_in[8];
  const float* b1 = (const float*)d_in[9];
  const float* W2 = (const float*)d_in[10];
  const float* b2 = (const float*)d_in[11];
  const float* W3 = (const float*)d_in[12];
  const float* b3 = (const float*)d_in[13];
  const float* W4 = (const float*)d_in[14];
  const float* b4 = (const float*)d_in[15];
  float* out = (float*)d_out;
  const int n_res = in_sizes[0];  // B*L = 32768

  float* tabAA = (float*)d_ws;                 // 21*256 floats
  float* tabCH = tabAA + N_AA * H1DIM;         // 10*256 floats

  hipLaunchKernelGGL(precompute_tables, dim3(N_AA + 10), dim3(256), 0, stream,
                     aa_emb, chain_emb, W1, b1, tabAA, tabCH);

  const int nblk = n_res / T;
  hipLaunchKernelGGL(residue_embed_kernel, dim3(nblk), dim3(512), 0, stream,
                     seq, xyz, orient, dihedrals, chain, amask, W1, W2, b2, W3,
                     b3, W4, b4, tabAA, tabCH, out, n_res);
}

// Round 4
// 131.886 us; speedup vs baseline: 1.4421x; 1.4124x over previous
//
#include <hip/hip_runtime.h>
#include <math.h>

#define N_AA 21
#define NATOM 15
#define DF 128
#define H1DIM 256
#define OFF_COORD 128
#define OFF_DIH 1073
#define OFF_CHAIN 1112
#define T 32
#define H1STR 260   // s_h1 row stride (float4-aligned)
#define BUFSTR 132  // s_buf2 row stride
#define DIH0 46     // dihedral enc start col inside s_buf2 row
#define NW1C 984    // bf16-copied W1 rows: [128,1112) = 945 coord + 39 dih
#define DIHROW 945  // dih rows offset inside w1c

__constant__ float c_freq[6] = {1.0f, 2.0f, 3.0f, 1.0f, 0.5f, 1.0f / 3.0f};

// uppercase macro params (lowercase `w` collided with the .w member)
#define FMA4(A, S, W)            \
  A.x = fmaf((S), (W).x, A.x);   \
  A.y = fmaf((S), (W).y, A.y);   \
  A.z = fmaf((S), (W).z, A.z);   \
  A.w = fmaf((S), (W).w, A.w);

__device__ inline float bf2f(unsigned short u) {
  union { unsigned int i; float f; } x;
  x.i = (unsigned)u << 16;
  return x.f;
}
__device__ inline float4 bf4_to_f4(ushort4 u) {
  float4 f;
  f.x = bf2f(u.x); f.y = bf2f(u.y); f.z = bf2f(u.z); f.w = bf2f(u.w);
  return f;
}
__device__ inline unsigned short f2bf(float f) {  // RNE
  unsigned int x = __float_as_uint(f);
  unsigned int r = (x + 0x7fffu + ((x >> 16) & 1u)) >> 16;
  return (unsigned short)r;
}

// tabAA[t][i] = sum_k aa_emb[t][k] * W1[k][i]
// tabCH[c][i] = b1[i] + sum_k chain_emb[c][k] * W1[OFF_CHAIN+k][i]
__global__ __launch_bounds__(256) void precompute_tables(
    const float* __restrict__ aa_emb, const float* __restrict__ chain_emb,
    const float* __restrict__ W1, const float* __restrict__ b1,
    float* __restrict__ tabAA, float* __restrict__ tabCH) {
  const int i = threadIdx.x;
  const int b = blockIdx.x;
  if (b < N_AA) {
    const float* e = aa_emb + b * DF;
    float acc = 0.f;
#pragma unroll 8
    for (int k = 0; k < DF; ++k) acc = fmaf(e[k], W1[k * H1DIM + i], acc);
    tabAA[b * H1DIM + i] = acc;
  } else {
    const int c = b - N_AA;
    const float* e = chain_emb + c * DF;
    float acc = b1[i];
#pragma unroll 8
    for (int k = 0; k < DF; ++k)
      acc = fmaf(e[k], W1[(OFF_CHAIN + k) * H1DIM + i], acc);
    tabCH[c * H1DIM + i] = acc;
  }
}

// bf16 copy of W1 rows [128, 1112): w1c[r][i] = bf16(W1[128+r][i])
__global__ __launch_bounds__(256) void convert_w1(const float* __restrict__ W1,
                                                  unsigned short* __restrict__ w1c) {
  const int r = blockIdx.x;
  const int i = threadIdx.x;
  w1c[r * H1DIM + i] = f2bf(W1[(OFF_COORD + r) * H1DIM + i]);
}

template <int USE_BF16>
__global__ __launch_bounds__(512, 4) void residue_embed_kernel(
    const int* __restrict__ seq_idx, const float* __restrict__ xyz,
    const float* __restrict__ orient, const float* __restrict__ dihedrals,
    const int* __restrict__ chain_idx, const float* __restrict__ amask,
    const float* __restrict__ W1, const float* __restrict__ W2,
    const float* __restrict__ b2, const float* __restrict__ W3,
    const float* __restrict__ b3, const float* __restrict__ W4,
    const float* __restrict__ b4, const float* __restrict__ tabAA,
    const float* __restrict__ tabCH, const unsigned short* __restrict__ w1c,
    float* __restrict__ out, int n_res) {
  __shared__ float s_h1[T][H1STR];    // h1; later h3 in cols 0..127
  __shared__ float s_buf2[T][BUFSTR]; // phase0: coord[0..44], dih[46..84]; later h2
  __shared__ float s_w[32 * DF];      // 16 KB weight staging chunk (32 rows x 128)
  __shared__ int s_t[T];
  __shared__ int s_c[T];

  const int tid = threadIdx.x;
  const int base = blockIdx.x * T;

  // ---- phase 0: indices, local coords, dihedral encoding ----
  if (tid < T) {
    s_t[tid] = seq_idx[base + tid];
    s_c[tid] = chain_idx[base + tid];
  }
  for (int idx = tid; idx < T * 45; idx += 512) {
    const int r = idx / 45, k = idx % 45;
    const int a = k / 3, i = k % 3;
    const int g = base + r;
    const float* X = xyz + g * 45;
    const float* R = orient + g * 9;
    const float m = amask[g * NATOM + a];
    float v = 0.f;
#pragma unroll
    for (int j = 0; j < 3; ++j)
      v = fmaf(R[j * 3 + i], X[a * 3 + j] - X[3 + j], v);  // CA = atom 1
    s_buf2[r][k] = v * m;
  }
  for (int idx = tid; idx < T * 39; idx += 512) {
    const int r = idx / 39, k = idx % 39;
    const int d = k / 13, m = k % 13;
    const float x = dihedrals[(base + r) * 3 + d];
    float v;
    if (m == 0)
      v = x;
    else if (m <= 6)
      v = sinf(c_freq[m - 1] * x);
    else
      v = cosf(c_freq[m - 7] * x);
    s_buf2[r][DIH0 + k] = v;
  }
  __syncthreads();

  // ---- layer 1: h1[T][256] = relu(feats @ W1 + b1), sparse-gathered ----
  {
    const int i0 = (tid & 63) * 4;  // 64 col groups cover 256 cols
    const int r0 = (tid >> 6) * 4;  // 8 residue groups of 4
    float4 acc[4];
#pragma unroll
    for (int rr = 0; rr < 4; ++rr) {
      const int t = s_t[r0 + rr], c = s_c[r0 + rr];
      const float4 a = *(const float4*)(tabAA + t * H1DIM + i0);
      const float4 b = *(const float4*)(tabCH + c * H1DIM + i0);
      acc[rr].x = a.x + b.x; acc[rr].y = a.y + b.y;
      acc[rr].z = a.z + b.z; acc[rr].w = a.w + b.w;
    }
    // dihedral rows (shared across residues)
#pragma unroll 3
    for (int k = 0; k < 39; ++k) {
      float4 wv;
      if (USE_BF16)
        wv = bf4_to_f4(*(const ushort4*)(w1c + (DIHROW + k) * H1DIM + i0));
      else
        wv = *(const float4*)(W1 + (OFF_DIH + k) * H1DIM + i0);
#pragma unroll
      for (int rr = 0; rr < 4; ++rr) {
        FMA4(acc[rr], s_buf2[r0 + rr][DIH0 + k], wv);
      }
    }
    // coord rows: 4 independent per-residue weight streams
    if (USE_BF16) {
      const unsigned short* wp[4];
#pragma unroll
      for (int rr = 0; rr < 4; ++rr)
        wp[rr] = w1c + (s_t[r0 + rr] * 45) * H1DIM + i0;
      for (int k = 0; k < 44; k += 2) {
#pragma unroll
        for (int rr = 0; rr < 4; ++rr) {
          const float2 a2 = *(const float2*)(&s_buf2[r0 + rr][k]);
          const float4 w0 = bf4_to_f4(*(const ushort4*)(wp[rr] + k * H1DIM));
          const float4 w1 = bf4_to_f4(*(const ushort4*)(wp[rr] + (k + 1) * H1DIM));
          FMA4(acc[rr], a2.x, w0);
          FMA4(acc[rr], a2.y, w1);
        }
      }
#pragma unroll
      for (int rr = 0; rr < 4; ++rr) {  // tail k = 44
        const float4 wv = bf4_to_f4(*(const ushort4*)(wp[rr] + 44 * H1DIM));
        FMA4(acc[rr], s_buf2[r0 + rr][44], wv);
      }
    } else {
      const float* wp[4];
#pragma unroll
      for (int rr = 0; rr < 4; ++rr)
        wp[rr] = W1 + (OFF_COORD + s_t[r0 + rr] * 45) * H1DIM + i0;
      for (int k = 0; k < 44; k += 2) {
#pragma unroll
        for (int rr = 0; rr < 4; ++rr) {
          const float2 a2 = *(const float2*)(&s_buf2[r0 + rr][k]);
          const float4 w0 = *(const float4*)(wp[rr] + k * H1DIM);
          const float4 w1 = *(const float4*)(wp[rr] + (k + 1) * H1DIM);
          FMA4(acc[rr], a2.x, w0);
          FMA4(acc[rr], a2.y, w1);
        }
      }
#pragma unroll
      for (int rr = 0; rr < 4; ++rr) {
        const float4 wv = *(const float4*)(wp[rr] + 44 * H1DIM);
        FMA4(acc[rr], s_buf2[r0 + rr][44], wv);
      }
    }
#pragma unroll
    for (int rr = 0; rr < 4; ++rr) {
      float4 v;
      v.x = fmaxf(acc[rr].x, 0.f);
      v.y = fmaxf(acc[rr].y, 0.f);
      v.z = fmaxf(acc[rr].z, 0.f);
      v.w = fmaxf(acc[rr].w, 0.f);
      *(float4*)(&s_h1[r0 + rr][i0]) = v;
    }
  }
  // NOTE: no barrier here — the first chunk barrier of layer 2 covers it.

  const int j0 = (tid & 31) * 4;  // 32 col groups cover 128 cols
  const int r2 = (tid >> 5) * 2;  // 16 residue groups of 2

  // ---- layer 2: h2 = relu(h1 @ W2 + b2), W2 LDS-staged in 32-row chunks ----
  {
    const float4 bb = *(const float4*)(b2 + j0);
    float4 acc0 = bb, acc1 = bb;
#pragma unroll 1
    for (int c = 0; c < 8; ++c) {
      __syncthreads();  // buffer free (and h1 visible for c==0)
      {
        const float* src = W2 + c * 32 * DF;
        const int idx = tid * 8;
        *(float4*)(&s_w[idx]) = *(const float4*)(src + idx);
        *(float4*)(&s_w[idx + 4]) = *(const float4*)(src + idx + 4);
      }
      __syncthreads();
      const int kb = c * 32;
#pragma unroll
      for (int kk = 0; kk < 32; kk += 4) {
        const float4 a0 = *(const float4*)(&s_h1[r2][kb + kk]);
        const float4 a1 = *(const float4*)(&s_h1[r2 + 1][kb + kk]);
        const float4 w0 = *(const float4*)(&s_w[(kk + 0) * DF + j0]);
        const float4 w1 = *(const float4*)(&s_w[(kk + 1) * DF + j0]);
        const float4 w2 = *(const float4*)(&s_w[(kk + 2) * DF + j0]);
        const float4 w3 = *(const float4*)(&s_w[(kk + 3) * DF + j0]);
        FMA4(acc0, a0.x, w0); FMA4(acc1, a1.x, w0);
        FMA4(acc0, a0.y, w1); FMA4(acc1, a1.y, w1);
        FMA4(acc0, a0.z, w2); FMA4(acc1, a1.z, w2);
        FMA4(acc0, a0.w, w3); FMA4(acc1, a1.w, w3);
      }
    }
    float4 v0, v1;
    v0.x = fmaxf(acc0.x, 0.f); v0.y = fmaxf(acc0.y, 0.f);
    v0.z = fmaxf(acc0.z, 0.f); v0.w = fmaxf(acc0.w, 0.f);
    v1.x = fmaxf(acc1.x, 0.f); v1.y = fmaxf(acc1.y, 0.f);
    v1.z = fmaxf(acc1.z, 0.f); v1.w = fmaxf(acc1.w, 0.f);
    *(float4*)(&s_buf2[r2][j0]) = v0;   // h2 (phase-0 data fully consumed)
    *(float4*)(&s_buf2[r2 + 1][j0]) = v1;
  }

  // ---- layer 3: h3 = relu(h2 @ W3 + b3) -> s_h1 cols 0..127 ----
  {
    const float4 bb = *(const float4*)(b3 + j0);
    float4 acc0 = bb, acc1 = bb;
#pragma unroll 1
    for (int c = 0; c < 4; ++c) {
      __syncthreads();  // buffer free + h2 visible for c==0
      {
        const float* src = W3 + c * 32 * DF;
        const int idx = tid * 8;
        *(float4*)(&s_w[idx]) = *(const float4*)(src + idx);
        *(float4*)(&s_w[idx + 4]) = *(const float4*)(src + idx + 4);
      }
      __syncthreads();
      const int kb = c * 32;
#pragma unroll
      for (int kk = 0; kk < 32; kk += 4) {
        const float4 a0 = *(const float4*)(&s_buf2[r2][kb + kk]);
        const float4 a1 = *(const float4*)(&s_buf2[r2 + 1][kb + kk]);
        const float4 w0 = *(const float4*)(&s_w[(kk + 0) * DF + j0]);
        const float4 w1 = *(const float4*)(&s_w[(kk + 1) * DF + j0]);
        const float4 w2 = *(const float4*)(&s_w[(kk + 2) * DF + j0]);
        const float4 w3 = *(const float4*)(&s_w[(kk + 3) * DF + j0]);
        FMA4(acc0, a0.x, w0); FMA4(acc1, a1.x, w0);
        FMA4(acc0, a0.y, w1); FMA4(acc1, a1.y, w1);
        FMA4(acc0, a0.z, w2); FMA4(acc1, a1.z, w2);
        FMA4(acc0, a0.w, w3); FMA4(acc1, a1.w, w3);
      }
    }
    float4 v0, v1;
    v0.x = fmaxf(acc0.x, 0.f); v0.y = fmaxf(acc0.y, 0.f);
    v0.z = fmaxf(acc0.z, 0.f); v0.w = fmaxf(acc0.w, 0.f);
    v1.x = fmaxf(acc1.x, 0.f); v1.y = fmaxf(acc1.y, 0.f);
    v1.z = fmaxf(acc1.z, 0.f); v1.w = fmaxf(acc1.w, 0.f);
    *(float4*)(&s_h1[r2][j0]) = v0;   // h3 (h1 fully consumed in layer 2)
    *(float4*)(&s_h1[r2 + 1][j0]) = v1;
  }

  // ---- layer 4: out = h3 @ W4 + b4 ----
  {
    const float4 bb = *(const float4*)(b4 + j0);
    float4 acc0 = bb, acc1 = bb;
#pragma unroll 1
    for (int c = 0; c < 4; ++c) {
      __syncthreads();
      {
        const float* src = W4 + c * 32 * DF;
        const int idx = tid * 8;
        *(float4*)(&s_w[idx]) = *(const float4*)(src + idx);
        *(float4*)(&s_w[idx + 4]) = *(const float4*)(src + idx + 4);
      }
      __syncthreads();
      const int kb = c * 32;
#pragma unroll
      for (int kk = 0; kk < 32; kk += 4) {
        const float4 a0 = *(const float4*)(&s_h1[r2][kb + kk]);
        const float4 a1 = *(const float4*)(&s_h1[r2 + 1][kb + kk]);
        const float4 w0 = *(const float4*)(&s_w[(kk + 0) * DF + j0]);
        const float4 w1 = *(const float4*)(&s_w[(kk + 1) * DF + j0]);
        const float4 w2 = *(const float4*)(&s_w[(kk + 2) * DF + j0]);
        const float4 w3 = *(const float4*)(&s_w[(kk + 3) * DF + j0]);
        FMA4(acc0, a0.x, w0); FMA4(acc1, a1.x, w0);
        FMA4(acc0, a0.y, w1); FMA4(acc1, a1.y, w1);
        FMA4(acc0, a0.z, w2); FMA4(acc1, a1.z, w2);
        FMA4(acc0, a0.w, w3); FMA4(acc1, a1.w, w3);
      }
    }
    *(float4*)(out + (size_t)(base + r2) * DF + j0) = acc0;
    *(float4*)(out + (size_t)(base + r2 + 1) * DF + j0) = acc1;
  }
}

extern "C" void kernel_launch(void* const* d_in, const int* in_sizes, int n_in,
                              void* d_out, int out_size, void* d_ws, size_t ws_size,
                              hipStream_t stream) {
  const int* seq = (const int*)d_in[0];
  const float* xyz = (const float*)d_in[1];
  const float* orient = (const float*)d_in[2];
  const float* dihedrals = (const float*)d_in[3];
  const int* chain = (const int*)d_in[4];
  const float* amask = (const float*)d_in[5];
  const float* aa_emb = (const float*)d_in[6];
  const float* chain_emb = (const float*)d_in[7];
  const float* W1 = (const float*)d_in[8];
  const float* b1 = (const float*)d_in[9];
  const float* W2 = (const float*)d_in[10];
  const float* b2 = (const float*)d_in[11];
  const float* W3 = (const float*)d_in[12];
  const float* b3 = (const float*)d_in[13];
  const float* W4 = (const float*)d_in[14];
  const float* b4 = (const float*)d_in[15];
  float* out = (float*)d_out;
  const int n_res = in_sizes[0];  // B*L = 32768

  float* tabAA = (float*)d_ws;                 // 21*256 floats
  float* tabCH = tabAA + N_AA * H1DIM;         // 10*256 floats
  const size_t tab_bytes = (size_t)(N_AA + 10) * H1DIM * sizeof(float);
  const size_t w1c_bytes = (size_t)NW1C * H1DIM * sizeof(unsigned short);
  const bool use_bf16 = ws_size >= tab_bytes + w1c_bytes;
  unsigned short* w1c =
      use_bf16 ? (unsigned short*)((char*)d_ws + tab_bytes) : nullptr;

  hipLaunchKernelGGL(precompute_tables, dim3(N_AA + 10), dim3(256), 0, stream,
                     aa_emb, chain_emb, W1, b1, tabAA, tabCH);
  if (use_bf16)
    hipLaunchKernelGGL(convert_w1, dim3(NW1C), dim3(256), 0, stream, W1, w1c);

  const int nblk = n_res / T;
  if (use_bf16)
    residue_embed_kernel<1><<<dim3(nblk), dim3(512), 0, stream>>>(
        seq, xyz, orient, dihedrals, chain, amask, W1, W2, b2, W3, b3, W4, b4,
        tabAA, tabCH, w1c, out, n_res);
  else
    residue_embed_kernel<0><<<dim3(nblk), dim3(512), 0, stream>>>(
        seq, xyz, orient, dihedrals, chain, amask, W1, W2, b2, W3, b3, W4, b4,
        tabAA, tabCH, nullptr, out, n_res);
}

// Round 6
// 96.608 us; speedup vs baseline: 1.9688x; 1.3652x over previous
//
#include <hip/hip_runtime.h>
#include <math.h>

#define N_AA 21
#define NATOM 15
#define DF 128
#define H1DIM 256
#define OFF_COORD 128
#define OFF_DIH 1073
#define OFF_CHAIN 1112
#define T 32
#define DIH0 46     // dihedral enc start col inside s_buf2 row (fp32 union view)
#define NW1C 984    // bf16-copied W1 rows: [128,1112) = 945 coord + 39 dih
#define DIHROW 945  // dih rows offset inside w1c
#define HS1 264     // h1/h3 LDS row stride (ushort): 528B -> bank step 4 (2-way, free)
#define HS2 136     // h2 LDS row stride (ushort): 272B -> bank step 4
#define WBS 40      // staged-W LDS row stride (ushort): 80B -> bank step 20 (2-way)
#define WTROW 512   // wt_hi/lo global row stride: [128 cols][512 k: W2|W3|W4]
#define WT_W3 256
#define WT_W4 384

typedef __attribute__((ext_vector_type(8))) short s16x8;
typedef __attribute__((ext_vector_type(4))) float f32x4;

__constant__ float c_freq[6] = {1.0f, 2.0f, 3.0f, 1.0f, 0.5f, 1.0f / 3.0f};

// uppercase macro params (lowercase `w` collided with the .w member)
#define FMA4(A, S, W)            \
  A.x = fmaf((S), (W).x, A.x);   \
  A.y = fmaf((S), (W).y, A.y);   \
  A.z = fmaf((S), (W).z, A.z);   \
  A.w = fmaf((S), (W).w, A.w);

__device__ inline float bf2f(unsigned short u) {
  union { unsigned int i; float f; } x;
  x.i = (unsigned)u << 16;
  return x.f;
}
__device__ inline float4 bf4_to_f4(ushort4 u) {
  float4 f;
  f.x = bf2f(u.x); f.y = bf2f(u.y); f.z = bf2f(u.z); f.w = bf2f(u.w);
  return f;
}
__device__ inline unsigned short f2bf(float f) {  // RNE
  unsigned int x = __float_as_uint(f);
  unsigned int r = (x + 0x7fffu + ((x >> 16) & 1u)) >> 16;
  return (unsigned short)r;
}

// ---------------- prep kernels ----------------
__global__ __launch_bounds__(256) void precompute_tables(
    const float* __restrict__ aa_emb, const float* __restrict__ chain_emb,
    const float* __restrict__ W1, const float* __restrict__ b1,
    float* __restrict__ tabAA, float* __restrict__ tabCH) {
  const int i = threadIdx.x;
  const int b = blockIdx.x;
  if (b < N_AA) {
    const float* e = aa_emb + b * DF;
    float acc = 0.f;
#pragma unroll 8
    for (int k = 0; k < DF; ++k) acc = fmaf(e[k], W1[k * H1DIM + i], acc);
    tabAA[b * H1DIM + i] = acc;
  } else {
    const int c = b - N_AA;
    const float* e = chain_emb + c * DF;
    float acc = b1[i];
#pragma unroll 8
    for (int k = 0; k < DF; ++k)
      acc = fmaf(e[k], W1[(OFF_CHAIN + k) * H1DIM + i], acc);
    tabCH[c * H1DIM + i] = acc;
  }
}

__global__ __launch_bounds__(256) void convert_w1(const float* __restrict__ W1,
                                                  unsigned short* __restrict__ w1c) {
  const int r = blockIdx.x;
  const int i = threadIdx.x;
  w1c[r * H1DIM + i] = f2bf(W1[(OFF_COORD + r) * H1DIM + i]);
}

// wt_hi/lo[j][k]: transposed, split bf16 of W2 (k 0..255), W3 (256..383), W4 (384..511)
__global__ __launch_bounds__(256) void convert_wt(
    const float* __restrict__ W2, const float* __restrict__ W3,
    const float* __restrict__ W4, unsigned short* __restrict__ wt_hi,
    unsigned short* __restrict__ wt_lo) {
  const int j = blockIdx.x;  // 0..127 output col
  for (int k = threadIdx.x; k < WTROW; k += 256) {
    float v;
    if (k < WT_W3) v = W2[k * DF + j];
    else if (k < WT_W4) v = W3[(k - WT_W3) * DF + j];
    else v = W4[(k - WT_W4) * DF + j];
    const unsigned short h = f2bf(v);
    wt_hi[j * WTROW + k] = h;
    wt_lo[j * WTROW + k] = f2bf(v - bf2f(h));
  }
}

// ---------------- main MFMA kernel ----------------
__global__ __launch_bounds__(512, 4) void residue_embed_mfma(
    const int* __restrict__ seq_idx, const float* __restrict__ xyz,
    const float* __restrict__ orient, const float* __restrict__ dihedrals,
    const int* __restrict__ chain_idx, const float* __restrict__ amask,
    const float* __restrict__ b2, const float* __restrict__ b3,
    const float* __restrict__ b4, const float* __restrict__ tabAA,
    const float* __restrict__ tabCH, const unsigned short* __restrict__ w1c,
    const unsigned short* __restrict__ wt_hi,
    const unsigned short* __restrict__ wt_lo, float* __restrict__ out) {
  __shared__ unsigned short s_h1hi[T][HS1];  // h1 hi; later h3 hi (cols 0..127)
  __shared__ unsigned short s_h1lo[T][HS1];  // h1 lo; later h3 lo
  __shared__ __align__(16) char s_u[2 * T * HS2 * 2];  // phase0 fp32 [32][132] | h2 hi/lo
  __shared__ unsigned short s_wbhi[DF][WBS];  // staged W chunk hi [col][k32]
  __shared__ unsigned short s_wblo[DF][WBS];
  __shared__ int s_t[T];
  __shared__ int s_c[T];

  float (*s_buf2)[132] = (float(*)[132])s_u;
  unsigned short (*s_h2hi)[HS2] = (unsigned short(*)[HS2])s_u;
  unsigned short (*s_h2lo)[HS2] = (unsigned short(*)[HS2])(s_u + T * HS2 * 2);

  const int tid = threadIdx.x;
  const int base = blockIdx.x * T;

  // ---- phase 0: indices, local coords, dihedral encoding ----
  if (tid < T) {
    s_t[tid] = seq_idx[base + tid];
    s_c[tid] = chain_idx[base + tid];
  }
  for (int idx = tid; idx < T * 45; idx += 512) {
    const int r = idx / 45, k = idx % 45;
    const int a = k / 3, i = k % 3;
    const int g = base + r;
    const float* X = xyz + g * 45;
    const float* R = orient + g * 9;
    const float m = amask[g * NATOM + a];
    float v = 0.f;
#pragma unroll
    for (int j = 0; j < 3; ++j)
      v = fmaf(R[j * 3 + i], X[a * 3 + j] - X[3 + j], v);  // CA = atom 1
    s_buf2[r][k] = v * m;
  }
  for (int idx = tid; idx < T * 39; idx += 512) {
    const int r = idx / 39, k = idx % 39;
    const int d = k / 13, m = k % 13;
    const float x = dihedrals[(base + r) * 3 + d];
    float v;
    if (m == 0)
      v = x;
    else if (m <= 6)
      v = sinf(c_freq[m - 1] * x);
    else
      v = cosf(c_freq[m - 7] * x);
    s_buf2[r][DIH0 + k] = v;
  }
  __syncthreads();

  // ---- layer 1 (fp32 VALU, sparse gather): h1 -> split bf16 hi/lo in LDS ----
  {
    const int i0 = (tid & 63) * 4;
    const int r0 = (tid >> 6) * 4;
    float4 acc[4];
#pragma unroll
    for (int rr = 0; rr < 4; ++rr) {
      const int t = s_t[r0 + rr], c = s_c[r0 + rr];
      const float4 a = *(const float4*)(tabAA + t * H1DIM + i0);
      const float4 b = *(const float4*)(tabCH + c * H1DIM + i0);
      acc[rr].x = a.x + b.x; acc[rr].y = a.y + b.y;
      acc[rr].z = a.z + b.z; acc[rr].w = a.w + b.w;
    }
#pragma unroll 3
    for (int k = 0; k < 39; ++k) {
      const float4 wv = bf4_to_f4(*(const ushort4*)(w1c + (DIHROW + k) * H1DIM + i0));
#pragma unroll
      for (int rr = 0; rr < 4; ++rr) {
        FMA4(acc[rr], s_buf2[r0 + rr][DIH0 + k], wv);
      }
    }
    const unsigned short* wp[4];
#pragma unroll
    for (int rr = 0; rr < 4; ++rr)
      wp[rr] = w1c + (s_t[r0 + rr] * 45) * H1DIM + i0;
    for (int k = 0; k < 44; k += 2) {
#pragma unroll
      for (int rr = 0; rr < 4; ++rr) {
        const float2 a2 = *(const float2*)(&s_buf2[r0 + rr][k]);
        const float4 w0 = bf4_to_f4(*(const ushort4*)(wp[rr] + k * H1DIM));
        const float4 w1 = bf4_to_f4(*(const ushort4*)(wp[rr] + (k + 1) * H1DIM));
        FMA4(acc[rr], a2.x, w0);
        FMA4(acc[rr], a2.y, w1);
      }
    }
#pragma unroll
    for (int rr = 0; rr < 4; ++rr) {
      const float4 wv = bf4_to_f4(*(const ushort4*)(wp[rr] + 44 * H1DIM));
      FMA4(acc[rr], s_buf2[r0 + rr][44], wv);
    }
#pragma unroll
    for (int rr = 0; rr < 4; ++rr) {
      ushort4 vh, vl;
      float v;
      v = fmaxf(acc[rr].x, 0.f); vh.x = f2bf(v); vl.x = f2bf(v - bf2f(vh.x));
      v = fmaxf(acc[rr].y, 0.f); vh.y = f2bf(v); vl.y = f2bf(v - bf2f(vh.y));
      v = fmaxf(acc[rr].z, 0.f); vh.z = f2bf(v); vl.z = f2bf(v - bf2f(vh.z));
      v = fmaxf(acc[rr].w, 0.f); vh.w = f2bf(v); vl.w = f2bf(v - bf2f(vh.w));
      *(ushort4*)(&s_h1hi[r0 + rr][i0]) = vh;
      *(ushort4*)(&s_h1lo[r0 + rr][i0]) = vl;
    }
  }
  // (first staging barrier of layer 2 makes h1 visible)

  // ---- MFMA tiling constants ----
  const int l = tid & 63;
  const int w = tid >> 6;           // wave 0..7
  const int mt = w & 1;             // M tile (residues 16*mt..)
  const int nc = w >> 1;            // 0..3 -> col tiles 2nc, 2nc+1
  const int nc0 = nc * 32;
  const int ar = 16 * mt + (l & 15);       // A row (residue) for this lane
  const int kb = (l >> 4) * 8;             // A/B k-offset within 32-chunk
  const int bc0 = nc0 + (l & 15);          // B col, tile 0
  const int bc1 = bc0 + 16;                // B col, tile 1
  const int drow = 16 * mt + (l >> 4) * 4; // D row base (+reg)
  const int jst = tid >> 2, seg = tid & 3; // staging: row jst, 16B segment seg

#define MFMA_LAYER(NCHUNK, WTOFF, SRCH, SRCL, SSTR, BPTR, EPI)                   \
  do {                                                                           \
    f32x4 acc0 = {0.f, 0.f, 0.f, 0.f}, acc1 = {0.f, 0.f, 0.f, 0.f};             \
    for (int c = 0; c < (NCHUNK); ++c) {                                         \
      __syncthreads();                                                           \
      {                                                                          \
        const int koff = (WTOFF) + c * 32 + seg * 8;                             \
        *(float4*)(&s_wbhi[jst][seg * 8]) =                                      \
            *(const float4*)(wt_hi + jst * WTROW + koff);                        \
        *(float4*)(&s_wblo[jst][seg * 8]) =                                      \
            *(const float4*)(wt_lo + jst * WTROW + koff);                        \
      }                                                                          \
      __syncthreads();                                                           \
      const int ko = c * 32 + kb;                                                \
      const s16x8 ah = *(const s16x8*)((SRCH) + ar * (SSTR) + ko);               \
      const s16x8 al = *(const s16x8*)((SRCL) + ar * (SSTR) + ko);               \
      const s16x8 b0h = *(const s16x8*)(&s_wbhi[bc0][kb]);                       \
      const s16x8 b0l = *(const s16x8*)(&s_wblo[bc0][kb]);                       \
      const s16x8 b1h = *(const s16x8*)(&s_wbhi[bc1][kb]);                       \
      const s16x8 b1l = *(const s16x8*)(&s_wblo[bc1][kb]);                       \
      acc0 = __builtin_amdgcn_mfma_f32_16x16x32_bf16(ah, b0h, acc0, 0, 0, 0);    \
      acc1 = __builtin_amdgcn_mfma_f32_16x16x32_bf16(ah, b1h, acc1, 0, 0, 0);    \
      acc0 = __builtin_amdgcn_mfma_f32_16x16x32_bf16(ah, b0l, acc0, 0, 0, 0);    \
      acc1 = __builtin_amdgcn_mfma_f32_16x16x32_bf16(ah, b1l, acc1, 0, 0, 0);    \
      acc0 = __builtin_amdgcn_mfma_f32_16x16x32_bf16(al, b0h, acc0, 0, 0, 0);    \
      acc1 = __builtin_amdgcn_mfma_f32_16x16x32_bf16(al, b1h, acc1, 0, 0, 0);    \
    }                                                                            \
    const float bias0 = (BPTR)[nc0 + (l & 15)];                                  \
    const float bias1 = (BPTR)[nc0 + 16 + (l & 15)];                             \
    EPI                                                                          \
  } while (0)

#define EPI_HIDDEN(DH, DL, DSTR)                                                 \
  {                                                                              \
    _Pragma("unroll")                                                            \
    for (int reg = 0; reg < 4; ++reg) {                                          \
      const int row = drow + reg;                                                \
      float v0 = fmaxf(acc0[reg] + bias0, 0.f);                                  \
      float v1 = fmaxf(acc1[reg] + bias1, 0.f);                                  \
      unsigned short h0 = f2bf(v0), h1v = f2bf(v1);                              \
      (DH)[row * (DSTR) + nc0 + (l & 15)] = h0;                                  \
      (DL)[row * (DSTR) + nc0 + (l & 15)] = f2bf(v0 - bf2f(h0));                 \
      (DH)[row * (DSTR) + nc0 + 16 + (l & 15)] = h1v;                            \
      (DL)[row * (DSTR) + nc0 + 16 + (l & 15)] = f2bf(v1 - bf2f(h1v));           \
    }                                                                            \
  }

  // ---- layer 2: h2 = relu(h1 @ W2 + b2), K=256 ----
  MFMA_LAYER(8, 0, &s_h1hi[0][0], &s_h1lo[0][0], HS1, b2,
             EPI_HIDDEN(&s_h2hi[0][0], &s_h2lo[0][0], HS2));

  // ---- layer 3: h3 = relu(h2 @ W3 + b3), K=128 -> overwrite s_h1 (consumed) ----
  MFMA_LAYER(4, WT_W3, &s_h2hi[0][0], &s_h2lo[0][0], HS2, b3,
             EPI_HIDDEN(&s_h1hi[0][0], &s_h1lo[0][0], HS1));

  // ---- layer 4: out = h3 @ W4 + b4 (no relu), K=128 ----
  MFMA_LAYER(4, WT_W4, &s_h1hi[0][0], &s_h1lo[0][0], HS1, b4, {
    _Pragma("unroll")
    for (int reg = 0; reg < 4; ++reg) {
      const int row = base + drow + reg;
      out[(size_t)row * DF + nc0 + (l & 15)] = acc0[reg] + bias0;
      out[(size_t)row * DF + nc0 + 16 + (l & 15)] = acc1[reg] + bias1;
    }
  });
}

// ---------------- fp32 fallback (round-4 structure, no workspace extras) ----------------
__global__ __launch_bounds__(512, 4) void residue_embed_fallback(
    const int* __restrict__ seq_idx, const float* __restrict__ xyz,
    const float* __restrict__ orient, const float* __restrict__ dihedrals,
    const int* __restrict__ chain_idx, const float* __restrict__ amask,
    const float* __restrict__ W1, const float* __restrict__ W2,
    const float* __restrict__ b2, const float* __restrict__ W3,
    const float* __restrict__ b3, const float* __restrict__ W4,
    const float* __restrict__ b4, const float* __restrict__ tabAA,
    const float* __restrict__ tabCH, float* __restrict__ out) {
  __shared__ float s_h1[T][260];
  __shared__ float s_buf2[T][132];
  __shared__ float s_w[32 * DF];
  __shared__ int s_t[T];
  __shared__ int s_c[T];

  const int tid = threadIdx.x;
  const int base = blockIdx.x * T;

  if (tid < T) {
    s_t[tid] = seq_idx[base + tid];
    s_c[tid] = chain_idx[base + tid];
  }
  for (int idx = tid; idx < T * 45; idx += 512) {
    const int r = idx / 45, k = idx % 45;
    const int a = k / 3, i = k % 3;
    const int g = base + r;
    const float* X = xyz + g * 45;
    const float* R = orient + g * 9;
    const float m = amask[g * NATOM + a];
    float v = 0.f;
#pragma unroll
    for (int j = 0; j < 3; ++j)
      v = fmaf(R[j * 3 + i], X[a * 3 + j] - X[3 + j], v);
    s_buf2[r][k] = v * m;
  }
  for (int idx = tid; idx < T * 39; idx += 512) {
    const int r = idx / 39, k = idx % 39;
    const int d = k / 13, m = k % 13;
    const float x = dihedrals[(base + r) * 3 + d];
    float v;
    if (m == 0) v = x;
    else if (m <= 6) v = sinf(c_freq[m - 1] * x);
    else v = cosf(c_freq[m - 7] * x);
    s_buf2[r][DIH0 + k] = v;
  }
  __syncthreads();
  {
    const int i0 = (tid & 63) * 4;
    const int r0 = (tid >> 6) * 4;
    float4 acc[4];
#pragma unroll
    for (int rr = 0; rr < 4; ++rr) {
      const int t = s_t[r0 + rr], c = s_c[r0 + rr];
      const float4 a = *(const float4*)(tabAA + t * H1DIM + i0);
      const float4 b = *(const float4*)(tabCH + c * H1DIM + i0);
      acc[rr].x = a.x + b.x; acc[rr].y = a.y + b.y;
      acc[rr].z = a.z + b.z; acc[rr].w = a.w + b.w;
    }
#pragma unroll 3
    for (int k = 0; k < 39; ++k) {
      const float4 wv = *(const float4*)(W1 + (OFF_DIH + k) * H1DIM + i0);
#pragma unroll
      for (int rr = 0; rr < 4; ++rr) {
        FMA4(acc[rr], s_buf2[r0 + rr][DIH0 + k], wv);
      }
    }
    const float* wp[4];
#pragma unroll
    for (int rr = 0; rr < 4; ++rr)
      wp[rr] = W1 + (OFF_COORD + s_t[r0 + rr] * 45) * H1DIM + i0;
    for (int k = 0; k < 45; ++k) {
#pragma unroll
      for (int rr = 0; rr < 4; ++rr) {
        const float4 wv = *(const float4*)(wp[rr] + k * H1DIM);
        FMA4(acc[rr], s_buf2[r0 + rr][k], wv);
      }
    }
#pragma unroll
    for (int rr = 0; rr < 4; ++rr) {
      float4 v;
      v.x = fmaxf(acc[rr].x, 0.f); v.y = fmaxf(acc[rr].y, 0.f);
      v.z = fmaxf(acc[rr].z, 0.f); v.w = fmaxf(acc[rr].w, 0.f);
      *(float4*)(&s_h1[r0 + rr][i0]) = v;
    }
  }
  const int j0 = (tid & 31) * 4;
  const int r2 = (tid >> 5) * 2;
#define FB_LAYER(NCH, WSRC, SRC, BPTR, STORE)                               \
  do {                                                                      \
    const float4 bb = *(const float4*)((BPTR) + j0);                        \
    float4 acc0 = bb, acc1 = bb;                                            \
    for (int c = 0; c < (NCH); ++c) {                                       \
      __syncthreads();                                                      \
      {                                                                     \
        const float* src = (WSRC) + c * 32 * DF;                            \
        const int idx = tid * 8;                                            \
        *(float4*)(&s_w[idx]) = *(const float4*)(src + idx);                \
        *(float4*)(&s_w[idx + 4]) = *(const float4*)(src + idx + 4);        \
      }                                                                     \
      __syncthreads();                                                      \
      const int kb2 = c * 32;                                               \
      _Pragma("unroll")                                                     \
      for (int kk = 0; kk < 32; kk += 4) {                                  \
        const float4 a0 = *(const float4*)(&(SRC)[r2][kb2 + kk]);           \
        const float4 a1 = *(const float4*)(&(SRC)[r2 + 1][kb2 + kk]);       \
        const float4 w0 = *(const float4*)(&s_w[(kk + 0) * DF + j0]);       \
        const float4 w1 = *(const float4*)(&s_w[(kk + 1) * DF + j0]);       \
        const float4 w2 = *(const float4*)(&s_w[(kk + 2) * DF + j0]);       \
        const float4 w3 = *(const float4*)(&s_w[(kk + 3) * DF + j0]);       \
        FMA4(acc0, a0.x, w0); FMA4(acc1, a1.x, w0);                         \
        FMA4(acc0, a0.y, w1); FMA4(acc1, a1.y, w1);                         \
        FMA4(acc0, a0.z, w2); FMA4(acc1, a1.z, w2);                         \
        FMA4(acc0, a0.w, w3); FMA4(acc1, a1.w, w3);                         \
      }                                                                     \
    }                                                                       \
    STORE                                                                   \
  } while (0)
#define RELU_STORE(DST)                                                     \
  {                                                                         \
    float4 v0, v1;                                                          \
    v0.x = fmaxf(acc0.x, 0.f); v0.y = fmaxf(acc0.y, 0.f);                   \
    v0.z = fmaxf(acc0.z, 0.f); v0.w = fmaxf(acc0.w, 0.f);                   \
    v1.x = fmaxf(acc1.x, 0.f); v1.y = fmaxf(acc1.y, 0.f);                   \
    v1.z = fmaxf(acc1.z, 0.f); v1.w = fmaxf(acc1.w, 0.f);                   \
    *(float4*)(&(DST)[r2][j0]) = v0;                                        \
    *(float4*)(&(DST)[r2 + 1][j0]) = v1;                                    \
  }
  FB_LAYER(8, W2, s_h1, b2, RELU_STORE(s_buf2));
  FB_LAYER(4, W3, s_buf2, b3, RELU_STORE(s_h1));
  FB_LAYER(4, W4, s_h1, b4, {
    *(float4*)(out + (size_t)(base + r2) * DF + j0) = acc0;
    *(float4*)(out + (size_t)(base + r2 + 1) * DF + j0) = acc1;
  });
}

extern "C" void kernel_launch(void* const* d_in, const int* in_sizes, int n_in,
                              void* d_out, int out_size, void* d_ws, size_t ws_size,
                              hipStream_t stream) {
  const int* seq = (const int*)d_in[0];
  const float* xyz = (const float*)d_in[1];
  const float* orient = (const float*)d_in[2];
  const float* dihedrals = (const float*)d_in[3];
  const int* chain = (const int*)d_in[4];
  const float* amask = (const float*)d_in[5];
  const float* aa_emb = (const float*)d_in[6];
  const float* chain_emb = (const float*)d_in[7];
  const float* W1 = (const float*)d_in[8];
  const float* b1 = (const float*)d_in[9];
  const float* W2 = (const float*)d_in[10];
  const float* b2 = (const float*)d_in[11];
  const float* W3 = (const float*)d_in[12];
  const float* b3 = (const float*)d_in[13];
  const float* W4 = (const float*)d_in[14];
  const float* b4 = (const float*)d_in[15];
  float* out = (float*)d_out;
  const int n_res = in_sizes[0];  // B*L = 32768

  char* wsp = (char*)d_ws;
  float* tabAA = (float*)wsp;                       // 21*256 f32
  float* tabCH = tabAA + N_AA * H1DIM;              // 10*256 f32
  const size_t tab_bytes = (size_t)(N_AA + 10) * H1DIM * sizeof(float);
  unsigned short* w1c = (unsigned short*)(wsp + tab_bytes);        // 984*256 us
  const size_t w1c_bytes = (size_t)NW1C * H1DIM * sizeof(unsigned short);
  unsigned short* wt_hi = (unsigned short*)(wsp + tab_bytes + w1c_bytes);
  unsigned short* wt_lo = wt_hi + DF * WTROW;
  const size_t wt_bytes = 2ull * DF * WTROW * sizeof(unsigned short);
  const bool use_mfma = ws_size >= tab_bytes + w1c_bytes + wt_bytes;

  hipLaunchKernelGGL(precompute_tables, dim3(N_AA + 10), dim3(256), 0, stream,
                     aa_emb, chain_emb, W1, b1, tabAA, tabCH);
  const int nblk = n_res / T;
  if (use_mfma) {
    hipLaunchKernelGGL(convert_w1, dim3(NW1C), dim3(256), 0, stream, W1, w1c);
    hipLaunchKernelGGL(convert_wt, dim3(DF), dim3(256), 0, stream, W2, W3, W4,
                       wt_hi, wt_lo);
    hipLaunchKernelGGL(residue_embed_mfma, dim3(nblk), dim3(512), 0, stream,
                       seq, xyz, orient, dihedrals, chain, amask, b2, b3, b4,
                       tabAA, tabCH, w1c, wt_hi, wt_lo, out);
  } else {
    hipLaunchKernelGGL(residue_embed_fallback, dim3(nblk), dim3(512), 0, stream,
                       seq, xyz, orient, dihedrals, chain, amask, W1, W2, b2,
                       W3, b3, W4, b4, tabAA, tabCH, out);
  }
}

// Round 7
// 90.885 us; speedup vs baseline: 2.0927x; 1.0630x over previous
//
#include <hip/hip_runtime.h>
#include <math.h>

#define N_AA 21
#define NATOM 15
#define DF 128
#define H1DIM 256
#define OFF_COORD 128
#define OFF_DIH 1073
#define OFF_CHAIN 1112
#define T 32
#define DIH0 46     // dihedral enc start col inside s_buf2 row (fp32 union view)
#define NW1C 984    // bf16-copied W1 rows: [128,1112) = 945 coord + 39 dih
#define DIHROW 945  // dih rows offset inside w1c
#define HS1 264     // h1/h3 LDS row stride (ushort): 528B = 33*16B -> 2-way max (free)
#define HS2 136     // h2 LDS row stride (ushort): 272B = 17*16B -> 2-way max
#define NFRAG_CH 16 // frag-packed chunks: 8 (W2) + 4 (W3) + 4 (W4)

typedef __attribute__((ext_vector_type(8))) short s16x8;
typedef __attribute__((ext_vector_type(4))) float f32x4;

__constant__ float c_freq[6] = {1.0f, 2.0f, 3.0f, 1.0f, 0.5f, 1.0f / 3.0f};

// uppercase macro params (lowercase `w` collided with the .w member)
#define FMA4(A, S, W)            \
  A.x = fmaf((S), (W).x, A.x);   \
  A.y = fmaf((S), (W).y, A.y);   \
  A.z = fmaf((S), (W).z, A.z);   \
  A.w = fmaf((S), (W).w, A.w);

__device__ inline float bf2f(unsigned short u) {
  union { unsigned int i; float f; } x;
  x.i = (unsigned)u << 16;
  return x.f;
}
__device__ inline float4 bf4_to_f4(ushort4 u) {
  float4 f;
  f.x = bf2f(u.x); f.y = bf2f(u.y); f.z = bf2f(u.z); f.w = bf2f(u.w);
  return f;
}
__device__ inline unsigned short f2bf(float f) {  // RNE
  unsigned int x = __float_as_uint(f);
  unsigned int r = (x + 0x7fffu + ((x >> 16) & 1u)) >> 16;
  return (unsigned short)r;
}

// ---------------- prep kernels ----------------
__global__ __launch_bounds__(256) void precompute_tables(
    const float* __restrict__ aa_emb, const float* __restrict__ chain_emb,
    const float* __restrict__ W1, const float* __restrict__ b1,
    float* __restrict__ tabAA, float* __restrict__ tabCH) {
  const int i = threadIdx.x;
  const int b = blockIdx.x;
  if (b < N_AA) {
    const float* e = aa_emb + b * DF;
    float acc = 0.f;
#pragma unroll 8
    for (int k = 0; k < DF; ++k) acc = fmaf(e[k], W1[k * H1DIM + i], acc);
    tabAA[b * H1DIM + i] = acc;
  } else {
    const int c = b - N_AA;
    const float* e = chain_emb + c * DF;
    float acc = b1[i];
#pragma unroll 8
    for (int k = 0; k < DF; ++k)
      acc = fmaf(e[k], W1[(OFF_CHAIN + k) * H1DIM + i], acc);
    tabCH[c * H1DIM + i] = acc;
  }
}

__global__ __launch_bounds__(256) void convert_w1(const float* __restrict__ W1,
                                                  unsigned short* __restrict__ w1c) {
  const int r = blockIdx.x;
  const int i = threadIdx.x;
  w1c[r * H1DIM + i] = f2bf(W1[(OFF_COORD + r) * H1DIM + i]);
}

// Fragment-packed split-bf16 weights for layers 2-4.
// Chunk-globals: cg 0..7 = W2 k-chunks, 8..11 = W3, 12..15 = W4.
// Element ((cg*8 + nt)*64 + lane)*8 + j  =  W[k][col],
//   col = nt*16 + (lane&15),  k = kbase + (lane>>4)*8 + j
// -> wave B-frag load is lane-contiguous 16B (perfectly coalesced, L2-resident).
__global__ __launch_bounds__(512) void convert_wfrag(
    const float* __restrict__ W2, const float* __restrict__ W3,
    const float* __restrict__ W4, unsigned short* __restrict__ wf_hi,
    unsigned short* __restrict__ wf_lo) {
  const int blk = blockIdx.x;  // cg*8 + nt
  const int cg = blk >> 3, nt = blk & 7;
  const float* W;
  int kbase;
  if (cg < 8) { W = W2; kbase = cg * 32; }
  else if (cg < 12) { W = W3; kbase = (cg - 8) * 32; }
  else { W = W4; kbase = (cg - 12) * 32; }
  const int l = threadIdx.x >> 3, j = threadIdx.x & 3 | (threadIdx.x & 7);
  const int jj = threadIdx.x & 7;
  const int col = nt * 16 + (l & 15);
  const int k = kbase + (l >> 4) * 8 + jj;
  const float v = W[k * DF + col];
  const unsigned short h = f2bf(v);
  const size_t o = ((size_t)blk * 64 + l) * 8 + jj;
  wf_hi[o] = h;
  wf_lo[o] = f2bf(v - bf2f(h));
  (void)j;
}

// ---------------- main MFMA kernel ----------------
__global__ __launch_bounds__(512, 4) void residue_embed_mfma(
    const int* __restrict__ seq_idx, const float* __restrict__ xyz,
    const float* __restrict__ orient, const float* __restrict__ dihedrals,
    const int* __restrict__ chain_idx, const float* __restrict__ amask,
    const float* __restrict__ b2, const float* __restrict__ b3,
    const float* __restrict__ b4, const float* __restrict__ tabAA,
    const float* __restrict__ tabCH, const unsigned short* __restrict__ w1c,
    const unsigned short* __restrict__ wf_hi,
    const unsigned short* __restrict__ wf_lo, float* __restrict__ out) {
  __shared__ unsigned short s_h1hi[T][HS1];  // h1 hi; later h3 hi (cols 0..127)
  __shared__ unsigned short s_h1lo[T][HS1];  // h1 lo; later h3 lo
  __shared__ __align__(16) char s_u[2 * T * HS2 * 2];  // phase0 fp32 [32][132] | h2 hi/lo
  __shared__ int s_t[T];
  __shared__ int s_c[T];

  float (*s_buf2)[132] = (float(*)[132])s_u;
  unsigned short (*s_h2hi)[HS2] = (unsigned short(*)[HS2])s_u;
  unsigned short (*s_h2lo)[HS2] = (unsigned short(*)[HS2])(s_u + T * HS2 * 2);

  const int tid = threadIdx.x;
  const int base = blockIdx.x * T;

  // ---- phase 0: indices, local coords, dihedral encoding ----
  if (tid < T) {
    s_t[tid] = seq_idx[base + tid];
    s_c[tid] = chain_idx[base + tid];
  }
  for (int idx = tid; idx < T * 45; idx += 512) {
    const int r = idx / 45, k = idx % 45;
    const int a = k / 3, i = k % 3;
    const int g = base + r;
    const float* X = xyz + g * 45;
    const float* R = orient + g * 9;
    const float m = amask[g * NATOM + a];
    float v = 0.f;
#pragma unroll
    for (int j = 0; j < 3; ++j)
      v = fmaf(R[j * 3 + i], X[a * 3 + j] - X[3 + j], v);  // CA = atom 1
    s_buf2[r][k] = v * m;
  }
  for (int idx = tid; idx < T * 39; idx += 512) {
    const int r = idx / 39, k = idx % 39;
    const int d = k / 13, m = k % 13;
    const float x = dihedrals[(base + r) * 3 + d];
    float v;
    if (m == 0)
      v = x;
    else if (m <= 6)
      v = sinf(c_freq[m - 1] * x);
    else
      v = cosf(c_freq[m - 7] * x);
    s_buf2[r][DIH0 + k] = v;
  }
  __syncthreads();

  // ---- layer 1 (fp32 VALU, sparse gather): h1 -> split bf16 hi/lo in LDS ----
  {
    const int i0 = (tid & 63) * 4;
    const int r0 = (tid >> 6) * 4;
    float4 acc[4];
#pragma unroll
    for (int rr = 0; rr < 4; ++rr) {
      const int t = s_t[r0 + rr], c = s_c[r0 + rr];
      const float4 a = *(const float4*)(tabAA + t * H1DIM + i0);
      const float4 b = *(const float4*)(tabCH + c * H1DIM + i0);
      acc[rr].x = a.x + b.x; acc[rr].y = a.y + b.y;
      acc[rr].z = a.z + b.z; acc[rr].w = a.w + b.w;
    }
#pragma unroll 3
    for (int k = 0; k < 39; ++k) {
      const float4 wv = bf4_to_f4(*(const ushort4*)(w1c + (DIHROW + k) * H1DIM + i0));
#pragma unroll
      for (int rr = 0; rr < 4; ++rr) {
        FMA4(acc[rr], s_buf2[r0 + rr][DIH0 + k], wv);
      }
    }
    const unsigned short* wp[4];
#pragma unroll
    for (int rr = 0; rr < 4; ++rr)
      wp[rr] = w1c + (s_t[r0 + rr] * 45) * H1DIM + i0;
    for (int k = 0; k < 44; k += 2) {
#pragma unroll
      for (int rr = 0; rr < 4; ++rr) {
        const float2 a2 = *(const float2*)(&s_buf2[r0 + rr][k]);
        const float4 w0 = bf4_to_f4(*(const ushort4*)(wp[rr] + k * H1DIM));
        const float4 w1 = bf4_to_f4(*(const ushort4*)(wp[rr] + (k + 1) * H1DIM));
        FMA4(acc[rr], a2.x, w0);
        FMA4(acc[rr], a2.y, w1);
      }
    }
#pragma unroll
    for (int rr = 0; rr < 4; ++rr) {
      const float4 wv = bf4_to_f4(*(const ushort4*)(wp[rr] + 44 * H1DIM));
      FMA4(acc[rr], s_buf2[r0 + rr][44], wv);
    }
#pragma unroll
    for (int rr = 0; rr < 4; ++rr) {
      ushort4 vh, vl;
      float v;
      v = fmaxf(acc[rr].x, 0.f); vh.x = f2bf(v); vl.x = f2bf(v - bf2f(vh.x));
      v = fmaxf(acc[rr].y, 0.f); vh.y = f2bf(v); vl.y = f2bf(v - bf2f(vh.y));
      v = fmaxf(acc[rr].z, 0.f); vh.z = f2bf(v); vl.z = f2bf(v - bf2f(vh.z));
      v = fmaxf(acc[rr].w, 0.f); vh.w = f2bf(v); vl.w = f2bf(v - bf2f(vh.w));
      *(ushort4*)(&s_h1hi[r0 + rr][i0]) = vh;
      *(ushort4*)(&s_h1lo[r0 + rr][i0]) = vl;
    }
  }
  __syncthreads();  // h1 visible to all waves

  // ---- MFMA tiling constants ----
  const int l = tid & 63;
  const int w = tid >> 6;           // wave 0..7
  const int mt = w & 1;             // M tile (residues 16*mt..)
  const int nc = w >> 1;            // 0..3 -> col tiles 2nc, 2nc+1
  const int nc0 = nc * 32;
  const int ar = 16 * mt + (l & 15);       // A row (residue) for this lane
  const int kb = (l >> 4) * 8;             // A/B k-offset within 32-chunk
  const int drow = 16 * mt + (l >> 4) * 4; // D row base (+reg)
  const size_t fbase = (size_t)(2 * nc) * 512 + (size_t)l * 8;  // frag lane offset

// B-fragments straight from global (L2-resident, coalesced 16B/lane). No
// barriers inside the chunk loop; loads pipeline across iterations.
#define MFMA_LAYER(NCHUNK, CG0, SRCH, SRCL, SSTR, BPTR, EPI)                     \
  do {                                                                           \
    f32x4 acc0 = {0.f, 0.f, 0.f, 0.f}, acc1 = {0.f, 0.f, 0.f, 0.f};             \
    const unsigned short* ph = wf_hi + (size_t)(CG0)*4096 + fbase;               \
    const unsigned short* pl = wf_lo + (size_t)(CG0)*4096 + fbase;               \
    _Pragma("unroll 2")                                                          \
    for (int c = 0; c < (NCHUNK); ++c) {                                         \
      const s16x8 b0h = *(const s16x8*)(ph + (size_t)c * 4096);                  \
      const s16x8 b1h = *(const s16x8*)(ph + (size_t)c * 4096 + 512);            \
      const s16x8 b0l = *(const s16x8*)(pl + (size_t)c * 4096);                  \
      const s16x8 b1l = *(const s16x8*)(pl + (size_t)c * 4096 + 512);            \
      const int ko = c * 32 + kb;                                                \
      const s16x8 ah = *(const s16x8*)((SRCH) + ar * (SSTR) + ko);               \
      const s16x8 al = *(const s16x8*)((SRCL) + ar * (SSTR) + ko);               \
      acc0 = __builtin_amdgcn_mfma_f32_16x16x32_bf16(ah, b0h, acc0, 0, 0, 0);    \
      acc1 = __builtin_amdgcn_mfma_f32_16x16x32_bf16(ah, b1h, acc1, 0, 0, 0);    \
      acc0 = __builtin_amdgcn_mfma_f32_16x16x32_bf16(ah, b0l, acc0, 0, 0, 0);    \
      acc1 = __builtin_amdgcn_mfma_f32_16x16x32_bf16(ah, b1l, acc1, 0, 0, 0);    \
      acc0 = __builtin_amdgcn_mfma_f32_16x16x32_bf16(al, b0h, acc0, 0, 0, 0);    \
      acc1 = __builtin_amdgcn_mfma_f32_16x16x32_bf16(al, b1h, acc1, 0, 0, 0);    \
    }                                                                            \
    const float bias0 = (BPTR)[nc0 + (l & 15)];                                  \
    const float bias1 = (BPTR)[nc0 + 16 + (l & 15)];                             \
    EPI                                                                          \
  } while (0)

#define EPI_HIDDEN(DH, DL, DSTR)                                                 \
  {                                                                              \
    _Pragma("unroll")                                                            \
    for (int reg = 0; reg < 4; ++reg) {                                          \
      const int row = drow + reg;                                                \
      float v0 = fmaxf(acc0[reg] + bias0, 0.f);                                  \
      float v1 = fmaxf(acc1[reg] + bias1, 0.f);                                  \
      unsigned short h0 = f2bf(v0), h1v = f2bf(v1);                              \
      (DH)[row * (DSTR) + nc0 + (l & 15)] = h0;                                  \
      (DL)[row * (DSTR) + nc0 + (l & 15)] = f2bf(v0 - bf2f(h0));                 \
      (DH)[row * (DSTR) + nc0 + 16 + (l & 15)] = h1v;                            \
      (DL)[row * (DSTR) + nc0 + 16 + (l & 15)] = f2bf(v1 - bf2f(h1v));           \
    }                                                                            \
  }

  // ---- layer 2: h2 = relu(h1 @ W2 + b2), K=256 ----
  MFMA_LAYER(8, 0, &s_h1hi[0][0], &s_h1lo[0][0], HS1, b2,
             EPI_HIDDEN(&s_h2hi[0][0], &s_h2lo[0][0], HS2));
  __syncthreads();  // h2 visible

  // ---- layer 3: h3 = relu(h2 @ W3 + b3), K=128 -> overwrite s_h1 (consumed) ----
  MFMA_LAYER(4, 8, &s_h2hi[0][0], &s_h2lo[0][0], HS2, b3,
             EPI_HIDDEN(&s_h1hi[0][0], &s_h1lo[0][0], HS1));
  __syncthreads();  // h3 visible

  // ---- layer 4: out = h3 @ W4 + b4 (no relu), K=128 ----
  MFMA_LAYER(4, 12, &s_h1hi[0][0], &s_h1lo[0][0], HS1, b4, {
    _Pragma("unroll")
    for (int reg = 0; reg < 4; ++reg) {
      const int row = base + drow + reg;
      out[(size_t)row * DF + nc0 + (l & 15)] = acc0[reg] + bias0;
      out[(size_t)row * DF + nc0 + 16 + (l & 15)] = acc1[reg] + bias1;
    }
  });
}

// ---------------- fp32 fallback (round-4 structure, no workspace extras) ----------------
__global__ __launch_bounds__(512, 4) void residue_embed_fallback(
    const int* __restrict__ seq_idx, const float* __restrict__ xyz,
    const float* __restrict__ orient, const float* __restrict__ dihedrals,
    const int* __restrict__ chain_idx, const float* __restrict__ amask,
    const float* __restrict__ W1, const float* __restrict__ W2,
    const float* __restrict__ b2, const float* __restrict__ W3,
    const float* __restrict__ b3, const float* __restrict__ W4,
    const float* __restrict__ b4, const float* __restrict__ tabAA,
    const float* __restrict__ tabCH, float* __restrict__ out) {
  __shared__ float s_h1[T][260];
  __shared__ float s_buf2[T][132];
  __shared__ float s_w[32 * DF];
  __shared__ int s_t[T];
  __shared__ int s_c[T];

  const int tid = threadIdx.x;
  const int base = blockIdx.x * T;

  if (tid < T) {
    s_t[tid] = seq_idx[base + tid];
    s_c[tid] = chain_idx[base + tid];
  }
  for (int idx = tid; idx < T * 45; idx += 512) {
    const int r = idx / 45, k = idx % 45;
    const int a = k / 3, i = k % 3;
    const int g = base + r;
    const float* X = xyz + g * 45;
    const float* R = orient + g * 9;
    const float m = amask[g * NATOM + a];
    float v = 0.f;
#pragma unroll
    for (int j = 0; j < 3; ++j)
      v = fmaf(R[j * 3 + i], X[a * 3 + j] - X[3 + j], v);
    s_buf2[r][k] = v * m;
  }
  for (int idx = tid; idx < T * 39; idx += 512) {
    const int r = idx / 39, k = idx % 39;
    const int d = k / 13, m = k % 13;
    const float x = dihedrals[(base + r) * 3 + d];
    float v;
    if (m == 0) v = x;
    else if (m <= 6) v = sinf(c_freq[m - 1] * x);
    else v = cosf(c_freq[m - 7] * x);
    s_buf2[r][DIH0 + k] = v;
  }
  __syncthreads();
  {
    const int i0 = (tid & 63) * 4;
    const int r0 = (tid >> 6) * 4;
    float4 acc[4];
#pragma unroll
    for (int rr = 0; rr < 4; ++rr) {
      const int t = s_t[r0 + rr], c = s_c[r0 + rr];
      const float4 a = *(const float4*)(tabAA + t * H1DIM + i0);
      const float4 b = *(const float4*)(tabCH + c * H1DIM + i0);
      acc[rr].x = a.x + b.x; acc[rr].y = a.y + b.y;
      acc[rr].z = a.z + b.z; acc[rr].w = a.w + b.w;
    }
#pragma unroll 3
    for (int k = 0; k < 39; ++k) {
      const float4 wv = *(const float4*)(W1 + (OFF_DIH + k) * H1DIM + i0);
#pragma unroll
      for (int rr = 0; rr < 4; ++rr) {
        FMA4(acc[rr], s_buf2[r0 + rr][DIH0 + k], wv);
      }
    }
    const float* wp[4];
#pragma unroll
    for (int rr = 0; rr < 4; ++rr)
      wp[rr] = W1 + (OFF_COORD + s_t[r0 + rr] * 45) * H1DIM + i0;
    for (int k = 0; k < 45; ++k) {
#pragma unroll
      for (int rr = 0; rr < 4; ++rr) {
        const float4 wv = *(const float4*)(wp[rr] + k * H1DIM);
        FMA4(acc[rr], s_buf2[r0 + rr][k], wv);
      }
    }
#pragma unroll
    for (int rr = 0; rr < 4; ++rr) {
      float4 v;
      v.x = fmaxf(acc[rr].x, 0.f); v.y = fmaxf(acc[rr].y, 0.f);
      v.z = fmaxf(acc[rr].z, 0.f); v.w = fmaxf(acc[rr].w, 0.f);
      *(float4*)(&s_h1[r0 + rr][i0]) = v;
    }
  }
  const int j0 = (tid & 31) * 4;
  const int r2 = (tid >> 5) * 2;
#define FB_LAYER(NCH, WSRC, SRC, BPTR, STORE)                               \
  do {                                                                      \
    const float4 bb = *(const float4*)((BPTR) + j0);                        \
    float4 acc0 = bb, acc1 = bb;                                            \
    for (int c = 0; c < (NCH); ++c) {                                       \
      __syncthreads();                                                      \
      {                                                                     \
        const float* src = (WSRC) + c * 32 * DF;                            \
        const int idx = tid * 8;                                            \
        *(float4*)(&s_w[idx]) = *(const float4*)(src + idx);                \
        *(float4*)(&s_w[idx + 4]) = *(const float4*)(src + idx + 4);        \
      }                                                                     \
      __syncthreads();                                                      \
      const int kb2 = c * 32;                                               \
      _Pragma("unroll")                                                     \
      for (int kk = 0; kk < 32; kk += 4) {                                  \
        const float4 a0 = *(const float4*)(&(SRC)[r2][kb2 + kk]);           \
        const float4 a1 = *(const float4*)(&(SRC)[r2 + 1][kb2 + kk]);       \
        const float4 w0 = *(const float4*)(&s_w[(kk + 0) * DF + j0]);       \
        const float4 w1 = *(const float4*)(&s_w[(kk + 1) * DF + j0]);       \
        const float4 w2 = *(const float4*)(&s_w[(kk + 2) * DF + j0]);       \
        const float4 w3 = *(const float4*)(&s_w[(kk + 3) * DF + j0]);       \
        FMA4(acc0, a0.x, w0); FMA4(acc1, a1.x, w0);                         \
        FMA4(acc0, a0.y, w1); FMA4(acc1, a1.y, w1);                         \
        FMA4(acc0, a0.z, w2); FMA4(acc1, a1.z, w2);                         \
        FMA4(acc0, a0.w, w3); FMA4(acc1, a1.w, w3);                         \
      }                                                                     \
    }                                                                       \
    STORE                                                                   \
  } while (0)
#define RELU_STORE(DST)                                                     \
  {                                                                         \
    float4 v0, v1;                                                          \
    v0.x = fmaxf(acc0.x, 0.f); v0.y = fmaxf(acc0.y, 0.f);                   \
    v0.z = fmaxf(acc0.z, 0.f); v0.w = fmaxf(acc0.w, 0.f);                   \
    v1.x = fmaxf(acc1.x, 0.f); v1.y = fmaxf(acc1.y, 0.f);                   \
    v1.z = fmaxf(acc1.z, 0.f); v1.w = fmaxf(acc1.w, 0.f);                   \
    *(float4*)(&(DST)[r2][j0]) = v0;                                        \
    *(float4*)(&(DST)[r2 + 1][j0]) = v1;                                    \
  }
  FB_LAYER(8, W2, s_h1, b2, RELU_STORE(s_buf2));
  FB_LAYER(4, W3, s_buf2, b3, RELU_STORE(s_h1));
  FB_LAYER(4, W4, s_h1, b4, {
    *(float4*)(out + (size_t)(base + r2) * DF + j0) = acc0;
    *(float4*)(out + (size_t)(base + r2 + 1) * DF + j0) = acc1;
  });
}

extern "C" void kernel_launch(void* const* d_in, const int* in_sizes, int n_in,
                              void* d_out, int out_size, void* d_ws, size_t ws_size,
                              hipStream_t stream) {
  const int* seq = (const int*)d_in[0];
  const float* xyz = (const float*)d_in[1];
  const float* orient = (const float*)d_in[2];
  const float* dihedrals = (const float*)d_in[3];
  const int* chain = (const int*)d_in[4];
  const float* amask = (const float*)d_in[5];
  const float* aa_emb = (const float*)d_in[6];
  const float* chain_emb = (const float*)d_in[7];
  const float* W1 = (const float*)d_in[8];
  const float* b1 = (const float*)d_in[9];
  const float* W2 = (const float*)d_in[10];
  const float* b2 = (const float*)d_in[11];
  const float* W3 = (const float*)d_in[12];
  const float* b3 = (const float*)d_in[13];
  const float* W4 = (const float*)d_in[14];
  const float* b4 = (const float*)d_in[15];
  float* out = (float*)d_out;
  const int n_res = in_sizes[0];  // B*L = 32768

  char* wsp = (char*)d_ws;
  float* tabAA = (float*)wsp;                       // 21*256 f32
  float* tabCH = tabAA + N_AA * H1DIM;              // 10*256 f32
  const size_t tab_bytes = (size_t)(N_AA + 10) * H1DIM * sizeof(float);
  unsigned short* w1c = (unsigned short*)(wsp + tab_bytes);        // 984*256 us
  const size_t w1c_bytes = (size_t)NW1C * H1DIM * sizeof(unsigned short);
  unsigned short* wf_hi = (unsigned short*)(wsp + tab_bytes + w1c_bytes);
  unsigned short* wf_lo = wf_hi + (size_t)NFRAG_CH * 8 * 512;
  const size_t wf_bytes = 2ull * NFRAG_CH * 8 * 512 * sizeof(unsigned short);
  const bool use_mfma = ws_size >= tab_bytes + w1c_bytes + wf_bytes;

  hipLaunchKernelGGL(precompute_tables, dim3(N_AA + 10), dim3(256), 0, stream,
                     aa_emb, chain_emb, W1, b1, tabAA, tabCH);
  const int nblk = n_res / T;
  if (use_mfma) {
    hipLaunchKernelGGL(convert_w1, dim3(NW1C), dim3(256), 0, stream, W1, w1c);
    hipLaunchKernelGGL(convert_wfrag, dim3(NFRAG_CH * 8), dim3(512), 0, stream,
                       W2, W3, W4, wf_hi, wf_lo);
    hipLaunchKernelGGL(residue_embed_mfma, dim3(nblk), dim3(512), 0, stream,
                       seq, xyz, orient, dihedrals, chain, amask, b2, b3, b4,
                       tabAA, tabCH, w1c, wf_hi, wf_lo, out);
  } else {
    hipLaunchKernelGGL(residue_embed_fallback, dim3(nblk), dim3(512), 0, stream,
                       seq, xyz, orient, dihedrals, chain, amask, W1, W2, b2,
                       W3, b3, W4, b4, tabAA, tabCH, out);
  }
}

// Round 8
// 73.835 us; speedup vs baseline: 2.5760x; 1.2309x over previous
//
#include <hip/hip_runtime.h>
#include <math.h>

#define N_AA 21
#define NATOM 15
#define DF 128
#define H1DIM 256
#define OFF_COORD 128
#define OFF_DIH 1073
#define OFF_CHAIN 1112
#define T 32
#define DIH0 46     // (fallback only) dihedral enc start col in fp32 buf
#define HS1 264     // h1/h3 LDS row stride (ushort): 528B -> 2-way max (free)
#define HS2 136     // h2 LDS row stride (ushort): 272B -> 2-way max
#define FS 104      // feature LDS row stride (ushort); 96 cols used (45 coord + 39 dih + 12 zero)
#define NFRAG_CH 16 // frag-packed chunks for W2|W3|W4
#define INVALID_IDX 0xFFFFFFFFu

typedef __attribute__((ext_vector_type(8))) short s16x8;
typedef __attribute__((ext_vector_type(4))) float f32x4;

__constant__ float c_freq[6] = {1.0f, 2.0f, 3.0f, 1.0f, 0.5f, 1.0f / 3.0f};

// uppercase macro params (lowercase `w` collided with the .w member)
#define FMA4(A, S, W)            \
  A.x = fmaf((S), (W).x, A.x);   \
  A.y = fmaf((S), (W).y, A.y);   \
  A.z = fmaf((S), (W).z, A.z);   \
  A.w = fmaf((S), (W).w, A.w);

__device__ inline float bf2f(unsigned short u) {
  union { unsigned int i; float f; } x;
  x.i = (unsigned)u << 16;
  return x.f;
}
__device__ inline unsigned short f2bf(float f) {  // RNE
  unsigned int x = __float_as_uint(f);
  unsigned int r = (x + 0x7fffu + ((x >> 16) & 1u)) >> 16;
  return (unsigned short)r;
}

// ---------------- prep kernels ----------------
__global__ __launch_bounds__(256) void precompute_tables(
    const float* __restrict__ aa_emb, const float* __restrict__ chain_emb,
    const float* __restrict__ W1, const float* __restrict__ b1,
    float* __restrict__ tabAA, float* __restrict__ tabCH) {
  const int i = threadIdx.x;
  const int b = blockIdx.x;
  if (b < N_AA) {
    const float* e = aa_emb + b * DF;
    float acc = 0.f;
#pragma unroll 8
    for (int k = 0; k < DF; ++k) acc = fmaf(e[k], W1[k * H1DIM + i], acc);
    tabAA[b * H1DIM + i] = acc;
  } else {
    const int c = b - N_AA;
    const float* e = chain_emb + c * DF;
    float acc = b1[i];
#pragma unroll 8
    for (int k = 0; k < DF; ++k)
      acc = fmaf(e[k], W1[(OFF_CHAIN + k) * H1DIM + i], acc);
    tabCH[c * H1DIM + i] = acc;
  }
}

// Fragment-packed split-bf16 weights for layers 2-4 (unchanged from r7).
__global__ __launch_bounds__(512) void convert_wfrag(
    const float* __restrict__ W2, const float* __restrict__ W3,
    const float* __restrict__ W4, unsigned short* __restrict__ wf_hi,
    unsigned short* __restrict__ wf_lo) {
  const int blk = blockIdx.x;  // cg*8 + nt
  const int cg = blk >> 3, nt = blk & 7;
  const float* W;
  int kbase;
  if (cg < 8) { W = W2; kbase = cg * 32; }
  else if (cg < 12) { W = W3; kbase = (cg - 8) * 32; }
  else { W = W4; kbase = (cg - 12) * 32; }
  const int l = threadIdx.x >> 3;
  const int jj = threadIdx.x & 7;
  const int col = nt * 16 + (l & 15);
  const int k = kbase + (l >> 4) * 8 + jj;
  const float v = W[k * DF + col];
  const unsigned short h = f2bf(v);
  const size_t o = ((size_t)blk * 64 + l) * 8 + jj;
  wf_hi[o] = h;
  wf_lo[o] = f2bf(v - bf2f(h));
}

// Per-type frag-packed bf16 W1 slice (coord 45 + dih 39, zero-pad to K=96).
// wl1[((t*3 + c)*16 + nt)*512 + l*8 + j]: col = nt*16 + (l&15),
// k = c*32 + (l>>4)*8 + j; k<45 -> coord row (t), 45<=k<84 -> dih row, else 0.
__global__ __launch_bounds__(512) void convert_wl1(const float* __restrict__ W1,
                                                   unsigned short* __restrict__ wl1) {
  const int t = blockIdx.x / 3, c = blockIdx.x % 3;
  for (int e = threadIdx.x; e < 16 * 512; e += 512) {
    const int nt = e >> 9, rem = e & 511;
    const int l = rem >> 3, j = rem & 7;
    const int col = nt * 16 + (l & 15);
    const int k = c * 32 + ((l >> 4) << 3) + j;
    float v = 0.f;
    if (k < 45) v = W1[(OFF_COORD + t * 45 + k) * H1DIM + col];
    else if (k < 84) v = W1[(OFF_DIH + (k - 45)) * H1DIM + col];
    wl1[(size_t)blockIdx.x * 8192 + (size_t)nt * 512 + rem] = f2bf(v);
  }
}

// ---------------- type-sort kernels ----------------
__global__ __launch_bounds__(256) void hist_kernel(const int* __restrict__ seq,
                                                   int n, int* __restrict__ counts) {
  __shared__ int h[N_AA];
  if (threadIdx.x < N_AA) h[threadIdx.x] = 0;
  __syncthreads();
  const int i = blockIdx.x * 256 + threadIdx.x;
  if (i < n) atomicAdd(&h[seq[i]], 1);
  __syncthreads();
  if (threadIdx.x < N_AA && h[threadIdx.x]) atomicAdd(&counts[threadIdx.x], h[threadIdx.x]);
}

__global__ void prefix_kernel(const int* __restrict__ counts, int* __restrict__ offsets) {
  if (threadIdx.x == 0) {
    int acc = 0;
    offsets[0] = 0;
    for (int t = 0; t < N_AA; ++t) {
      acc += (counts[t] + 15) & ~15;  // pad each type to multiple of 16
      offsets[t + 1] = acc;
    }
  }
}

__global__ __launch_bounds__(256) void scatter_kernel(
    const int* __restrict__ seq, int n, const int* __restrict__ offsets,
    int* __restrict__ fill, unsigned int* __restrict__ perm) {
  __shared__ int h[N_AA];
  __shared__ int basebuf[N_AA];
  if (threadIdx.x < N_AA) h[threadIdx.x] = 0;
  __syncthreads();
  const int i = blockIdx.x * 256 + threadIdx.x;
  int t = 0, slot = 0;
  const bool valid = i < n;
  if (valid) { t = seq[i]; slot = atomicAdd(&h[t], 1); }
  __syncthreads();
  if (threadIdx.x < N_AA && h[threadIdx.x])
    basebuf[threadIdx.x] = atomicAdd(&fill[threadIdx.x], h[threadIdx.x]);
  __syncthreads();
  if (valid) perm[offsets[t] + basebuf[t] + slot] = (unsigned int)i;
}

// ---------------- main kernel: all 4 layers MFMA over type-sorted rows ----------------
__global__ __launch_bounds__(512, 4) void residue_embed_sorted(
    const float* __restrict__ xyz, const float* __restrict__ orient,
    const float* __restrict__ dihedrals, const int* __restrict__ chain_idx,
    const float* __restrict__ amask, const float* __restrict__ b2,
    const float* __restrict__ b3, const float* __restrict__ b4,
    const float* __restrict__ tabAA, const float* __restrict__ tabCH,
    const unsigned short* __restrict__ wl1, const unsigned short* __restrict__ wf_hi,
    const unsigned short* __restrict__ wf_lo, const int* __restrict__ offsets,
    const unsigned int* __restrict__ perm, float* __restrict__ out) {
  __shared__ unsigned short s_h1hi[T][HS1];  // h1 hi; later h3 hi (cols 0..127)
  __shared__ unsigned short s_h1lo[T][HS1];
  __shared__ __align__(16) char s_u[2 * T * HS2 * 2];  // feat hi/lo | h2 hi/lo
  __shared__ unsigned int s_g[T];
  __shared__ int s_c[T];
  __shared__ int s_off[N_AA + 1];

  unsigned short (*s_fh)[FS] = (unsigned short(*)[FS])s_u;
  unsigned short (*s_fl)[FS] = (unsigned short(*)[FS])(s_u + T * FS * 2);
  unsigned short (*s_h2hi)[HS2] = (unsigned short(*)[HS2])s_u;
  unsigned short (*s_h2lo)[HS2] = (unsigned short(*)[HS2])(s_u + T * HS2 * 2);

  const int tid = threadIdx.x;
  const int base = blockIdx.x * T;

  if (tid < T) s_g[tid] = perm[base + tid];
  if (tid < N_AA + 1) s_off[tid] = offsets[tid];
  __syncthreads();

  // ---- phase 0: gather inputs via perm; features -> split bf16 LDS ----
  if (tid < T) {
    const unsigned int g = s_g[tid];
    s_c[tid] = (g != INVALID_IDX) ? chain_idx[g] : 0;
  }
  for (int idx = tid; idx < T * 45; idx += 512) {
    const int r = idx / 45, k = idx % 45;
    const int a = k / 3, i = k % 3;
    const unsigned int g = s_g[r];
    float v = 0.f;
    if (g != INVALID_IDX) {
      const float* X = xyz + (size_t)g * 45;
      const float* R = orient + (size_t)g * 9;
      const float m = amask[(size_t)g * NATOM + a];
#pragma unroll
      for (int j = 0; j < 3; ++j)
        v = fmaf(R[j * 3 + i], X[a * 3 + j] - X[3 + j], v);  // CA = atom 1
      v *= m;
    }
    const unsigned short h = f2bf(v);
    s_fh[r][k] = h;
    s_fl[r][k] = f2bf(v - bf2f(h));
  }
  for (int idx = tid; idx < T * 39; idx += 512) {
    const int r = idx / 39, kk = idx % 39;
    const int d = kk / 13, m = kk % 13;
    const unsigned int g = s_g[r];
    float v = 0.f;
    if (g != INVALID_IDX) {
      const float x = dihedrals[(size_t)g * 3 + d];
      if (m == 0) v = x;
      else if (m <= 6) v = sinf(c_freq[m - 1] * x);
      else v = cosf(c_freq[m - 7] * x);
    }
    const unsigned short h = f2bf(v);
    s_fh[r][45 + kk] = h;
    s_fl[r][45 + kk] = f2bf(v - bf2f(h));
  }
  for (int idx = tid; idx < T * 12; idx += 512) {  // zero pad k 84..95 (NaN-safety)
    const int r = idx / 12, k = 84 + idx % 12;
    s_fh[r][k] = 0;
    s_fl[r][k] = 0;
  }
  __syncthreads();

  // ---- MFMA tiling constants ----
  const int l = tid & 63;
  const int w = tid >> 6;            // wave 0..7
  const int mt = w & 1;              // M tile
  const int nc = w >> 1;             // 0..3
  const int nc0 = nc * 32;           // layers 2-4 col base (DF=128)
  const int ar = 16 * mt + (l & 15);
  const int kb = (l >> 4) * 8;
  const int drow = 16 * mt + (l >> 4) * 4;
  const size_t fbase = (size_t)(2 * nc) * 512 + (size_t)l * 8;

  // tile type (type-pure by construction)
  const int tstart = base + mt * 16;
  int ty = 0;
#pragma unroll
  for (int t2 = 1; t2 < N_AA; ++t2)
    if (tstart >= s_off[t2]) ty = t2;

  // ---- layer 1: h1 = relu(feat96 @ W1type + tabAA[ty] + tabCH[chain]) ----
  {
    f32x4 acc[4] = {{0.f, 0.f, 0.f, 0.f}, {0.f, 0.f, 0.f, 0.f},
                    {0.f, 0.f, 0.f, 0.f}, {0.f, 0.f, 0.f, 0.f}};
    s16x8 ah[3], al[3];
#pragma unroll
    for (int c = 0; c < 3; ++c) {
      ah[c] = *(const s16x8*)(&s_fh[ar][c * 32 + kb]);
      al[c] = *(const s16x8*)(&s_fl[ar][c * 32 + kb]);
    }
    const unsigned short* pB = wl1 + ((size_t)ty * 48 + 4 * nc) * 512 + (size_t)l * 8;
#pragma unroll
    for (int c = 0; c < 3; ++c) {
#pragma unroll
      for (int nt2 = 0; nt2 < 4; ++nt2) {
        const s16x8 bb = *(const s16x8*)(pB + ((size_t)c * 16 + nt2) * 512);
        acc[nt2] = __builtin_amdgcn_mfma_f32_16x16x32_bf16(ah[c], bb, acc[nt2], 0, 0, 0);
        acc[nt2] = __builtin_amdgcn_mfma_f32_16x16x32_bf16(al[c], bb, acc[nt2], 0, 0, 0);
      }
    }
#pragma unroll
    for (int nt2 = 0; nt2 < 4; ++nt2) {
      const int col0 = nc * 64 + nt2 * 16 + (l & 15);
      const float ta = tabAA[ty * H1DIM + col0];
#pragma unroll
      for (int reg = 0; reg < 4; ++reg) {
        const int row = drow + reg;
        float v = acc[nt2][reg] + ta + tabCH[s_c[row] * H1DIM + col0];
        v = fmaxf(v, 0.f);
        const unsigned short h = f2bf(v);
        s_h1hi[row][col0] = h;
        s_h1lo[row][col0] = f2bf(v - bf2f(h));
      }
    }
  }
  __syncthreads();  // h1 visible

#define MFMA_LAYER(NCHUNK, CG0, SRCH, SRCL, SSTR, BPTR, EPI)                     \
  do {                                                                           \
    f32x4 acc0 = {0.f, 0.f, 0.f, 0.f}, acc1 = {0.f, 0.f, 0.f, 0.f};             \
    const unsigned short* ph = wf_hi + (size_t)(CG0)*4096 + fbase;               \
    const unsigned short* pl = wf_lo + (size_t)(CG0)*4096 + fbase;               \
    _Pragma("unroll 2")                                                          \
    for (int c = 0; c < (NCHUNK); ++c) {                                         \
      const s16x8 b0h = *(const s16x8*)(ph + (size_t)c * 4096);                  \
      const s16x8 b1h = *(const s16x8*)(ph + (size_t)c * 4096 + 512);            \
      const s16x8 b0l = *(const s16x8*)(pl + (size_t)c * 4096);                  \
      const s16x8 b1l = *(const s16x8*)(pl + (size_t)c * 4096 + 512);            \
      const int ko = c * 32 + kb;                                                \
      const s16x8 ah = *(const s16x8*)((SRCH) + ar * (SSTR) + ko);               \
      const s16x8 al = *(const s16x8*)((SRCL) + ar * (SSTR) + ko);               \
      acc0 = __builtin_amdgcn_mfma_f32_16x16x32_bf16(ah, b0h, acc0, 0, 0, 0);    \
      acc1 = __builtin_amdgcn_mfma_f32_16x16x32_bf16(ah, b1h, acc1, 0, 0, 0);    \
      acc0 = __builtin_amdgcn_mfma_f32_16x16x32_bf16(ah, b0l, acc0, 0, 0, 0);    \
      acc1 = __builtin_amdgcn_mfma_f32_16x16x32_bf16(ah, b1l, acc1, 0, 0, 0);    \
      acc0 = __builtin_amdgcn_mfma_f32_16x16x32_bf16(al, b0h, acc0, 0, 0, 0);    \
      acc1 = __builtin_amdgcn_mfma_f32_16x16x32_bf16(al, b1h, acc1, 0, 0, 0);    \
    }                                                                            \
    const float bias0 = (BPTR)[nc0 + (l & 15)];                                  \
    const float bias1 = (BPTR)[nc0 + 16 + (l & 15)];                             \
    EPI                                                                          \
  } while (0)

#define EPI_HIDDEN(DH, DL, DSTR)                                                 \
  {                                                                              \
    _Pragma("unroll")                                                            \
    for (int reg = 0; reg < 4; ++reg) {                                          \
      const int row = drow + reg;                                                \
      float v0 = fmaxf(acc0[reg] + bias0, 0.f);                                  \
      float v1 = fmaxf(acc1[reg] + bias1, 0.f);                                  \
      unsigned short h0 = f2bf(v0), h1v = f2bf(v1);                              \
      (DH)[row * (DSTR) + nc0 + (l & 15)] = h0;                                  \
      (DL)[row * (DSTR) + nc0 + (l & 15)] = f2bf(v0 - bf2f(h0));                 \
      (DH)[row * (DSTR) + nc0 + 16 + (l & 15)] = h1v;                            \
      (DL)[row * (DSTR) + nc0 + 16 + (l & 15)] = f2bf(v1 - bf2f(h1v));           \
    }                                                                            \
  }

  // ---- layer 2: K=256 ----
  MFMA_LAYER(8, 0, &s_h1hi[0][0], &s_h1lo[0][0], HS1, b2,
             EPI_HIDDEN(&s_h2hi[0][0], &s_h2lo[0][0], HS2));
  __syncthreads();

  // ---- layer 3: K=128 -> overwrite s_h1 ----
  MFMA_LAYER(4, 8, &s_h2hi[0][0], &s_h2lo[0][0], HS2, b3,
             EPI_HIDDEN(&s_h1hi[0][0], &s_h1lo[0][0], HS1));
  __syncthreads();

  // ---- layer 4: K=128, scatter-store via perm ----
  MFMA_LAYER(4, 12, &s_h1hi[0][0], &s_h1lo[0][0], HS1, b4, {
    _Pragma("unroll")
    for (int reg = 0; reg < 4; ++reg) {
      const unsigned int g = s_g[drow + reg];
      if (g != INVALID_IDX) {
        out[(size_t)g * DF + nc0 + (l & 15)] = acc0[reg] + bias0;
        out[(size_t)g * DF + nc0 + 16 + (l & 15)] = acc1[reg] + bias1;
      }
    }
  });
}

// ---------------- fp32 fallback ----------------
__global__ __launch_bounds__(512, 4) void residue_embed_fallback(
    const int* __restrict__ seq_idx, const float* __restrict__ xyz,
    const float* __restrict__ orient, const float* __restrict__ dihedrals,
    const int* __restrict__ chain_idx, const float* __restrict__ amask,
    const float* __restrict__ W1, const float* __restrict__ W2,
    const float* __restrict__ b2, const float* __restrict__ W3,
    const float* __restrict__ b3, const float* __restrict__ W4,
    const float* __restrict__ b4, const float* __restrict__ tabAA,
    const float* __restrict__ tabCH, float* __restrict__ out) {
  __shared__ float s_h1[T][260];
  __shared__ float s_buf2[T][132];
  __shared__ float s_w[32 * DF];
  __shared__ int s_t[T];
  __shared__ int s_c[T];

  const int tid = threadIdx.x;
  const int base = blockIdx.x * T;

  if (tid < T) {
    s_t[tid] = seq_idx[base + tid];
    s_c[tid] = chain_idx[base + tid];
  }
  for (int idx = tid; idx < T * 45; idx += 512) {
    const int r = idx / 45, k = idx % 45;
    const int a = k / 3, i = k % 3;
    const int g = base + r;
    const float* X = xyz + g * 45;
    const float* R = orient + g * 9;
    const float m = amask[g * NATOM + a];
    float v = 0.f;
#pragma unroll
    for (int j = 0; j < 3; ++j)
      v = fmaf(R[j * 3 + i], X[a * 3 + j] - X[3 + j], v);
    s_buf2[r][k] = v * m;
  }
  for (int idx = tid; idx < T * 39; idx += 512) {
    const int r = idx / 39, k = idx % 39;
    const int d = k / 13, m = k % 13;
    const float x = dihedrals[(base + r) * 3 + d];
    float v;
    if (m == 0) v = x;
    else if (m <= 6) v = sinf(c_freq[m - 1] * x);
    else v = cosf(c_freq[m - 7] * x);
    s_buf2[r][DIH0 + k] = v;
  }
  __syncthreads();
  {
    const int i0 = (tid & 63) * 4;
    const int r0 = (tid >> 6) * 4;
    float4 acc[4];
#pragma unroll
    for (int rr = 0; rr < 4; ++rr) {
      const int t = s_t[r0 + rr], c = s_c[r0 + rr];
      const float4 a = *(const float4*)(tabAA + t * H1DIM + i0);
      const float4 b = *(const float4*)(tabCH + c * H1DIM + i0);
      acc[rr].x = a.x + b.x; acc[rr].y = a.y + b.y;
      acc[rr].z = a.z + b.z; acc[rr].w = a.w + b.w;
    }
#pragma unroll 3
    for (int k = 0; k < 39; ++k) {
      const float4 wv = *(const float4*)(W1 + (OFF_DIH + k) * H1DIM + i0);
#pragma unroll
      for (int rr = 0; rr < 4; ++rr) {
        FMA4(acc[rr], s_buf2[r0 + rr][DIH0 + k], wv);
      }
    }
    const float* wp[4];
#pragma unroll
    for (int rr = 0; rr < 4; ++rr)
      wp[rr] = W1 + (OFF_COORD + s_t[r0 + rr] * 45) * H1DIM + i0;
    for (int k = 0; k < 45; ++k) {
#pragma unroll
      for (int rr = 0; rr < 4; ++rr) {
        const float4 wv = *(const float4*)(wp[rr] + k * H1DIM);
        FMA4(acc[rr], s_buf2[r0 + rr][k], wv);
      }
    }
#pragma unroll
    for (int rr = 0; rr < 4; ++rr) {
      float4 v;
      v.x = fmaxf(acc[rr].x, 0.f); v.y = fmaxf(acc[rr].y, 0.f);
      v.z = fmaxf(acc[rr].z, 0.f); v.w = fmaxf(acc[rr].w, 0.f);
      *(float4*)(&s_h1[r0 + rr][i0]) = v;
    }
  }
  const int j0 = (tid & 31) * 4;
  const int r2 = (tid >> 5) * 2;
#define FB_LAYER(NCH, WSRC, SRC, BPTR, STORE)                               \
  do {                                                                      \
    const float4 bb = *(const float4*)((BPTR) + j0);                        \
    float4 acc0 = bb, acc1 = bb;                                            \
    for (int c = 0; c < (NCH); ++c) {                                       \
      __syncthreads();                                                      \
      {                                                                     \
        const float* src = (WSRC) + c * 32 * DF;                            \
        const int idx = tid * 8;                                            \
        *(float4*)(&s_w[idx]) = *(const float4*)(src + idx);                \
        *(float4*)(&s_w[idx + 4]) = *(const float4*)(src + idx + 4);        \
      }                                                                     \
      __syncthreads();                                                      \
      const int kb2 = c * 32;                                               \
      _Pragma("unroll")                                                     \
      for (int kk = 0; kk < 32; kk += 4) {                                  \
        const float4 a0 = *(const float4*)(&(SRC)[r2][kb2 + kk]);           \
        const float4 a1 = *(const float4*)(&(SRC)[r2 + 1][kb2 + kk]);       \
        const float4 w0 = *(const float4*)(&s_w[(kk + 0) * DF + j0]);       \
        const float4 w1 = *(const float4*)(&s_w[(kk + 1) * DF + j0]);       \
        const float4 w2 = *(const float4*)(&s_w[(kk + 2) * DF + j0]);       \
        const float4 w3 = *(const float4*)(&s_w[(kk + 3) * DF + j0]);       \
        FMA4(acc0, a0.x, w0); FMA4(acc1, a1.x, w0);                         \
        FMA4(acc0, a0.y, w1); FMA4(acc1, a1.y, w1);                         \
        FMA4(acc0, a0.z, w2); FMA4(acc1, a1.z, w2);                         \
        FMA4(acc0, a0.w, w3); FMA4(acc1, a1.w, w3);                         \
      }                                                                     \
    }                                                                       \
    STORE                                                                   \
  } while (0)
#define RELU_STORE(DST)                                                     \
  {                                                                         \
    float4 v0, v1;                                                          \
    v0.x = fmaxf(acc0.x, 0.f); v0.y = fmaxf(acc0.y, 0.f);                   \
    v0.z = fmaxf(acc0.z, 0.f); v0.w = fmaxf(acc0.w, 0.f);                   \
    v1.x = fmaxf(acc1.x, 0.f); v1.y = fmaxf(acc1.y, 0.f);                   \
    v1.z = fmaxf(acc1.z, 0.f); v1.w = fmaxf(acc1.w, 0.f);                   \
    *(float4*)(&(DST)[r2][j0]) = v0;                                        \
    *(float4*)(&(DST)[r2 + 1][j0]) = v1;                                    \
  }
  FB_LAYER(8, W2, s_h1, b2, RELU_STORE(s_buf2));
  FB_LAYER(4, W3, s_buf2, b3, RELU_STORE(s_h1));
  FB_LAYER(4, W4, s_h1, b4, {
    *(float4*)(out + (size_t)(base + r2) * DF + j0) = acc0;
    *(float4*)(out + (size_t)(base + r2 + 1) * DF + j0) = acc1;
  });
}

extern "C" void kernel_launch(void* const* d_in, const int* in_sizes, int n_in,
                              void* d_out, int out_size, void* d_ws, size_t ws_size,
                              hipStream_t stream) {
  const int* seq = (const int*)d_in[0];
  const float* xyz = (const float*)d_in[1];
  const float* orient = (const float*)d_in[2];
  const float* dihedrals = (const float*)d_in[3];
  const int* chain = (const int*)d_in[4];
  const float* amask = (const float*)d_in[5];
  const float* aa_emb = (const float*)d_in[6];
  const float* chain_emb = (const float*)d_in[7];
  const float* W1 = (const float*)d_in[8];
  const float* b1 = (const float*)d_in[9];
  const float* W2 = (const float*)d_in[10];
  const float* b2 = (const float*)d_in[11];
  const float* W3 = (const float*)d_in[12];
  const float* b3 = (const float*)d_in[13];
  const float* W4 = (const float*)d_in[14];
  const float* b4 = (const float*)d_in[15];
  float* out = (float*)d_out;
  const int n_res = in_sizes[0];  // B*L = 32768

  // ---- ws layout ----
  char* wsp = (char*)d_ws;
  const size_t o_tabAA = 0;
  const size_t o_tabCH = o_tabAA + (size_t)N_AA * H1DIM * 4;     // 21504
  const size_t o_wfhi = (o_tabCH + (size_t)10 * H1DIM * 4 + 255) & ~255ull;
  const size_t o_wflo = o_wfhi + (size_t)NFRAG_CH * 8 * 512 * 2;  // 131072 each
  const size_t o_wl1 = o_wflo + (size_t)NFRAG_CH * 8 * 512 * 2;
  const size_t wl1_bytes = (size_t)N_AA * 3 * 16 * 512 * 2;       // 1032192
  const size_t o_cnt = (o_wl1 + wl1_bytes + 255) & ~255ull;       // counts[21] + fill[21]
  const size_t o_offs = (o_cnt + 2 * N_AA * 4 + 255) & ~255ull;   // offsets[22]
  const size_t o_perm = (o_offs + (N_AA + 1) * 4 + 255) & ~255ull;
  const int npad_max = n_res + N_AA * 15;
  const int nblkB = (npad_max + T - 1) / T;
  const size_t perm_bytes = (size_t)nblkB * T * 4;
  const size_t need = o_perm + perm_bytes;

  float* tabAA = (float*)(wsp + o_tabAA);
  float* tabCH = (float*)(wsp + o_tabCH);

  hipLaunchKernelGGL(precompute_tables, dim3(N_AA + 10), dim3(256), 0, stream,
                     aa_emb, chain_emb, W1, b1, tabAA, tabCH);

  if (ws_size >= need) {
    unsigned short* wf_hi = (unsigned short*)(wsp + o_wfhi);
    unsigned short* wf_lo = (unsigned short*)(wsp + o_wflo);
    unsigned short* wl1 = (unsigned short*)(wsp + o_wl1);
    int* counts = (int*)(wsp + o_cnt);
    int* fill = counts + N_AA;
    int* offsets = (int*)(wsp + o_offs);
    unsigned int* perm = (unsigned int*)(wsp + o_perm);

    hipMemsetAsync(counts, 0, 2 * N_AA * 4, stream);
    hipMemsetAsync(perm, 0xFF, perm_bytes, stream);

    hipLaunchKernelGGL(convert_wfrag, dim3(NFRAG_CH * 8), dim3(512), 0, stream,
                       W2, W3, W4, wf_hi, wf_lo);
    hipLaunchKernelGGL(convert_wl1, dim3(N_AA * 3), dim3(512), 0, stream, W1, wl1);

    const int nblkH = (n_res + 255) / 256;
    hipLaunchKernelGGL(hist_kernel, dim3(nblkH), dim3(256), 0, stream, seq, n_res, counts);
    hipLaunchKernelGGL(prefix_kernel, dim3(1), dim3(64), 0, stream, counts, offsets);
    hipLaunchKernelGGL(scatter_kernel, dim3(nblkH), dim3(256), 0, stream, seq,
                       n_res, offsets, fill, perm);

    hipLaunchKernelGGL(residue_embed_sorted, dim3(nblkB), dim3(512), 0, stream,
                       xyz, orient, dihedrals, chain, amask, b2, b3, b4, tabAA,
                       tabCH, wl1, wf_hi, wf_lo, offsets, perm, out);
  } else {
    const int nblk = n_res / T;
    hipLaunchKernelGGL(residue_embed_fallback, dim3(nblk), dim3(512), 0, stream,
                       seq, xyz, orient, dihedrals, chain, amask, W1, W2, b2,
                       W3, b3, W4, b4, tabAA, tabCH, out);
  }
}

// Round 9
// 66.205 us; speedup vs baseline: 2.8728x; 1.1152x over previous
//
#include <hip/hip_runtime.h>
#include <math.h>

#define N_AA 21
#define NATOM 15
#define DF 128
#define H1DIM 256
#define OFF_COORD 128
#define OFF_DIH 1073
#define OFF_CHAIN 1112
#define T 32
#define DIH0 46     // (fallback only) dihedral enc start col in fp32 buf
#define HS1 264     // h1/h3 LDS row stride (ushort): 528B -> 2-way max (free)
#define HS2 136     // h2 LDS row stride (ushort): 272B -> 2-way max
#define FS 104      // feature LDS row stride (ushort); 96 cols used
#define NFRAG_CH 16 // frag-packed chunks for W2|W3|W4
#define INVALID_IDX 0xFFFFFFFFu

// prep_all role boundaries (blocks)
#define PR_TAB 31
#define PR_WF 256
#define PR_WL 63
#define PR_HIST 128  // ceil(32768/256)

typedef __attribute__((ext_vector_type(8))) short s16x8;
typedef __attribute__((ext_vector_type(4))) float f32x4;

__constant__ float c_freq[6] = {1.0f, 2.0f, 3.0f, 1.0f, 0.5f, 1.0f / 3.0f};

// uppercase macro params (lowercase `w` collided with the .w member)
#define FMA4(A, S, W)            \
  A.x = fmaf((S), (W).x, A.x);   \
  A.y = fmaf((S), (W).y, A.y);   \
  A.z = fmaf((S), (W).z, A.z);   \
  A.w = fmaf((S), (W).w, A.w;)
#undef FMA4
#define FMA4(A, S, W)            \
  A.x = fmaf((S), (W).x, A.x);   \
  A.y = fmaf((S), (W).y, A.y);   \
  A.z = fmaf((S), (W).z, A.z);   \
  A.w = fmaf((S), (W).w, A.w);

__device__ inline float bf2f(unsigned short u) {
  union { unsigned int i; float f; } x;
  x.i = (unsigned)u << 16;
  return x.f;
}
__device__ inline unsigned short f2bf(float f) {  // RNE
  unsigned int x = __float_as_uint(f);
  unsigned int r = (x + 0x7fffu + ((x >> 16) & 1u)) >> 16;
  return (unsigned short)r;
}

// ---------------- fused prep kernel ----------------
// roles: [0,31) tables | [31,287) wfrag | [287,350) wl1 | [350,350+PR_HIST) hist
__global__ __launch_bounds__(256) void prep_all(
    const float* __restrict__ aa_emb, const float* __restrict__ chain_emb,
    const float* __restrict__ W1, const float* __restrict__ b1,
    const float* __restrict__ W2, const float* __restrict__ W3,
    const float* __restrict__ W4, const int* __restrict__ seq, int n,
    float* __restrict__ tabAA, float* __restrict__ tabCH,
    unsigned short* __restrict__ wf_hi, unsigned short* __restrict__ wf_lo,
    unsigned short* __restrict__ wl1, int* __restrict__ counts) {
  const int b = blockIdx.x;
  if (b < PR_TAB) {
    // tabAA[t][i] / tabCH[c][i]
    const int i = threadIdx.x;
    if (b < N_AA) {
      const float* e = aa_emb + b * DF;
      float acc = 0.f;
#pragma unroll 8
      for (int k = 0; k < DF; ++k) acc = fmaf(e[k], W1[k * H1DIM + i], acc);
      tabAA[b * H1DIM + i] = acc;
    } else {
      const int c = b - N_AA;
      const float* e = chain_emb + c * DF;
      float acc = b1[i];
#pragma unroll 8
      for (int k = 0; k < DF; ++k)
        acc = fmaf(e[k], W1[(OFF_CHAIN + k) * H1DIM + i], acc);
      tabCH[c * H1DIM + i] = acc;
    }
  } else if (b < PR_TAB + PR_WF) {
    // frag-packed split-bf16 W2|W3|W4
    const int e = (b - PR_TAB) * 256 + threadIdx.x;  // < 65536
    const int blk = e >> 9;                          // orig chunk-block 0..127
    const int rem = e & 511;
    const int l = rem >> 3, jj = rem & 7;
    const int cg = blk >> 3, nt = blk & 7;
    const float* W;
    int kbase;
    if (cg < 8) { W = W2; kbase = cg * 32; }
    else if (cg < 12) { W = W3; kbase = (cg - 8) * 32; }
    else { W = W4; kbase = (cg - 12) * 32; }
    const int col = nt * 16 + (l & 15);
    const int k = kbase + (l >> 4) * 8 + jj;
    const float v = W[k * DF + col];
    const unsigned short h = f2bf(v);
    const size_t o = (size_t)blk * 512 + rem;
    wf_hi[o] = h;
    wf_lo[o] = f2bf(v - bf2f(h));
  } else if (b < PR_TAB + PR_WF + PR_WL) {
    // per-type frag-packed bf16 W1 slice (K=96 padded)
    const int b2 = b - PR_TAB - PR_WF;  // 0..62
    const int t = b2 / 3, c = b2 % 3;
    for (int e = threadIdx.x; e < 16 * 512; e += 256) {
      const int nt = e >> 9, rem = e & 511;
      const int l = rem >> 3, j = rem & 7;
      const int col = nt * 16 + (l & 15);
      const int k = c * 32 + ((l >> 4) << 3) + j;
      float v = 0.f;
      if (k < 45) v = W1[(OFF_COORD + t * 45 + k) * H1DIM + col];
      else if (k < 84) v = W1[(OFF_DIH + (k - 45)) * H1DIM + col];
      wl1[(size_t)b2 * 8192 + (size_t)nt * 512 + rem] = f2bf(v);
    }
  } else {
    // histogram (LDS-aggregated)
    __shared__ int h[N_AA];
    if (threadIdx.x < N_AA) h[threadIdx.x] = 0;
    __syncthreads();
    const int i = (b - PR_TAB - PR_WF - PR_WL) * 256 + threadIdx.x;
    if (i < n) atomicAdd(&h[seq[i]], 1);
    __syncthreads();
    if (threadIdx.x < N_AA && h[threadIdx.x])
      atomicAdd(&counts[threadIdx.x], h[threadIdx.x]);
  }
}

// ---------------- scatter + pad-fill (prefix computed locally) ----------------
// blocks [0,21): pad type t | block 21: tail fill | [22, 22+nblkH): scatter
__global__ __launch_bounds__(256) void scatter_pad(
    const int* __restrict__ seq, int n, int cap, const int* __restrict__ counts,
    int* __restrict__ fill, unsigned int* __restrict__ perm) {
  __shared__ int s_cnt[N_AA];
  __shared__ int s_off[N_AA + 1];
  __shared__ int h[N_AA];
  __shared__ int basebuf[N_AA];
  if (threadIdx.x < N_AA) s_cnt[threadIdx.x] = counts[threadIdx.x];
  __syncthreads();
  if (threadIdx.x == 0) {
    int acc = 0;
    s_off[0] = 0;
    for (int t = 0; t < N_AA; ++t) {
      acc += (s_cnt[t] + 15) & ~15;
      s_off[t + 1] = acc;
    }
  }
  __syncthreads();
  const int b = blockIdx.x;
  if (b < N_AA) {
    const int padstart = s_off[b] + s_cnt[b];
    const int padcnt = s_off[b + 1] - padstart;
    if ((int)threadIdx.x < padcnt) perm[padstart + threadIdx.x] = INVALID_IDX;
  } else if (b == N_AA) {
    for (int i = s_off[N_AA] + threadIdx.x; i < cap; i += 256)
      perm[i] = INVALID_IDX;
  } else {
    if (threadIdx.x < N_AA) h[threadIdx.x] = 0;
    __syncthreads();
    const int i = (b - N_AA - 1) * 256 + threadIdx.x;
    int t = 0, slot = 0;
    const bool valid = i < n;
    if (valid) { t = seq[i]; slot = atomicAdd(&h[t], 1); }
    __syncthreads();
    if (threadIdx.x < N_AA && h[threadIdx.x])
      basebuf[threadIdx.x] = atomicAdd(&fill[threadIdx.x], h[threadIdx.x]);
    __syncthreads();
    if (valid) perm[s_off[t] + basebuf[t] + slot] = (unsigned int)i;
  }
}

// ---------------- main kernel: all 4 layers MFMA over type-sorted rows ----------------
__global__ __launch_bounds__(512, 4) void residue_embed_sorted(
    const float* __restrict__ xyz, const float* __restrict__ orient,
    const float* __restrict__ dihedrals, const int* __restrict__ chain_idx,
    const float* __restrict__ amask, const float* __restrict__ b2,
    const float* __restrict__ b3, const float* __restrict__ b4,
    const float* __restrict__ tabAA, const float* __restrict__ tabCH,
    const unsigned short* __restrict__ wl1, const unsigned short* __restrict__ wf_hi,
    const unsigned short* __restrict__ wf_lo, const int* __restrict__ counts,
    const unsigned int* __restrict__ perm, float* __restrict__ out) {
  __shared__ unsigned short s_h1hi[T][HS1];  // h1 hi; later h3 hi (cols 0..127)
  __shared__ unsigned short s_h1lo[T][HS1];
  __shared__ __align__(16) char s_u[2 * T * HS2 * 2];  // feat hi/lo | h2 hi/lo
  __shared__ unsigned int s_g[T];
  __shared__ int s_c[T];
  __shared__ int s_off[N_AA + 1];
  __shared__ int s_cnt[N_AA];

  unsigned short (*s_fh)[FS] = (unsigned short(*)[FS])s_u;
  unsigned short (*s_fl)[FS] = (unsigned short(*)[FS])(s_u + T * FS * 2);
  unsigned short (*s_h2hi)[HS2] = (unsigned short(*)[HS2])s_u;
  unsigned short (*s_h2lo)[HS2] = (unsigned short(*)[HS2])(s_u + T * HS2 * 2);

  const int tid = threadIdx.x;
  const int base = blockIdx.x * T;

  if (tid < T) s_g[tid] = perm[base + tid];
  if (tid >= 64 && tid < 64 + N_AA) s_cnt[tid - 64] = counts[tid - 64];
  __syncthreads();
  if (tid == 0) {
    int acc = 0;
    s_off[0] = 0;
    for (int t = 0; t < N_AA; ++t) {
      acc += (s_cnt[t] + 15) & ~15;
      s_off[t + 1] = acc;
    }
  }

  // ---- phase 0: gather inputs via perm; features -> split bf16 LDS ----
  if (tid < T) {
    const unsigned int g = s_g[tid];
    s_c[tid] = (g != INVALID_IDX) ? chain_idx[g] : 0;
  }
  for (int idx = tid; idx < T * 45; idx += 512) {
    const int r = idx / 45, k = idx % 45;
    const int a = k / 3, i = k % 3;
    const unsigned int g = s_g[r];
    float v = 0.f;
    if (g != INVALID_IDX) {
      const float* X = xyz + (size_t)g * 45;
      const float* R = orient + (size_t)g * 9;
      const float m = amask[(size_t)g * NATOM + a];
#pragma unroll
      for (int j = 0; j < 3; ++j)
        v = fmaf(R[j * 3 + i], X[a * 3 + j] - X[3 + j], v);  // CA = atom 1
      v *= m;
    }
    const unsigned short h = f2bf(v);
    s_fh[r][k] = h;
    s_fl[r][k] = f2bf(v - bf2f(h));
  }
  for (int idx = tid; idx < T * 39; idx += 512) {
    const int r = idx / 39, kk = idx % 39;
    const int d = kk / 13, m = kk % 13;
    const unsigned int g = s_g[r];
    float v = 0.f;
    if (g != INVALID_IDX) {
      const float x = dihedrals[(size_t)g * 3 + d];
      if (m == 0) v = x;
      else if (m <= 6) v = sinf(c_freq[m - 1] * x);
      else v = cosf(c_freq[m - 7] * x);
    }
    const unsigned short h = f2bf(v);
    s_fh[r][45 + kk] = h;
    s_fl[r][45 + kk] = f2bf(v - bf2f(h));
  }
  for (int idx = tid; idx < T * 12; idx += 512) {  // zero pad k 84..95
    const int r = idx / 12, k = 84 + idx % 12;
    s_fh[r][k] = 0;
    s_fl[r][k] = 0;
  }
  __syncthreads();

  // ---- MFMA tiling constants ----
  const int l = tid & 63;
  const int w = tid >> 6;            // wave 0..7
  const int mt = w & 1;              // M tile
  const int nc = w >> 1;             // 0..3
  const int nc0 = nc * 32;           // layers 2-4 col base (DF=128)
  const int ar = 16 * mt + (l & 15);
  const int kb = (l >> 4) * 8;
  const int drow = 16 * mt + (l >> 4) * 4;
  const size_t fbase = (size_t)(2 * nc) * 512 + (size_t)l * 8;

  // tile type (type-pure by construction)
  const int tstart = base + mt * 16;
  int ty = 0;
#pragma unroll
  for (int t2 = 1; t2 < N_AA; ++t2)
    if (tstart >= s_off[t2]) ty = t2;

  // ---- layer 1: h1 = relu(feat96 @ W1type + tabAA[ty] + tabCH[chain]) ----
  {
    f32x4 acc[4] = {{0.f, 0.f, 0.f, 0.f}, {0.f, 0.f, 0.f, 0.f},
                    {0.f, 0.f, 0.f, 0.f}, {0.f, 0.f, 0.f, 0.f}};
    s16x8 ah[3], al[3];
#pragma unroll
    for (int c = 0; c < 3; ++c) {
      ah[c] = *(const s16x8*)(&s_fh[ar][c * 32 + kb]);
      al[c] = *(const s16x8*)(&s_fl[ar][c * 32 + kb]);
    }
    const unsigned short* pB = wl1 + ((size_t)ty * 48 + 4 * nc) * 512 + (size_t)l * 8;
#pragma unroll
    for (int c = 0; c < 3; ++c) {
#pragma unroll
      for (int nt2 = 0; nt2 < 4; ++nt2) {
        const s16x8 bb = *(const s16x8*)(pB + ((size_t)c * 16 + nt2) * 512);
        acc[nt2] = __builtin_amdgcn_mfma_f32_16x16x32_bf16(ah[c], bb, acc[nt2], 0, 0, 0);
        acc[nt2] = __builtin_amdgcn_mfma_f32_16x16x32_bf16(al[c], bb, acc[nt2], 0, 0, 0);
      }
    }
#pragma unroll
    for (int nt2 = 0; nt2 < 4; ++nt2) {
      const int col0 = nc * 64 + nt2 * 16 + (l & 15);
      const float ta = tabAA[ty * H1DIM + col0];
#pragma unroll
      for (int reg = 0; reg < 4; ++reg) {
        const int row = drow + reg;
        float v = acc[nt2][reg] + ta + tabCH[s_c[row] * H1DIM + col0];
        v = fmaxf(v, 0.f);
        const unsigned short h = f2bf(v);
        s_h1hi[row][col0] = h;
        s_h1lo[row][col0] = f2bf(v - bf2f(h));
      }
    }
  }
  __syncthreads();  // h1 visible

#define MFMA_LAYER(NCHUNK, CG0, SRCH, SRCL, SSTR, BPTR, EPI)                     \
  do {                                                                           \
    f32x4 acc0 = {0.f, 0.f, 0.f, 0.f}, acc1 = {0.f, 0.f, 0.f, 0.f};             \
    const unsigned short* ph = wf_hi + (size_t)(CG0)*4096 + fbase;               \
    const unsigned short* pl = wf_lo + (size_t)(CG0)*4096 + fbase;               \
    _Pragma("unroll 2")                                                          \
    for (int c = 0; c < (NCHUNK); ++c) {                                         \
      const s16x8 b0h = *(const s16x8*)(ph + (size_t)c * 4096);                  \
      const s16x8 b1h = *(const s16x8*)(ph + (size_t)c * 4096 + 512);            \
      const s16x8 b0l = *(const s16x8*)(pl + (size_t)c * 4096);                  \
      const s16x8 b1l = *(const s16x8*)(pl + (size_t)c * 4096 + 512);            \
      const int ko = c * 32 + kb;                                                \
      const s16x8 ah = *(const s16x8*)((SRCH) + ar * (SSTR) + ko);               \
      const s16x8 al = *(const s16x8*)((SRCL) + ar * (SSTR) + ko);               \
      acc0 = __builtin_amdgcn_mfma_f32_16x16x32_bf16(ah, b0h, acc0, 0, 0, 0);    \
      acc1 = __builtin_amdgcn_mfma_f32_16x16x32_bf16(ah, b1h, acc1, 0, 0, 0);    \
      acc0 = __builtin_amdgcn_mfma_f32_16x16x32_bf16(ah, b0l, acc0, 0, 0, 0);    \
      acc1 = __builtin_amdgcn_mfma_f32_16x16x32_bf16(ah, b1l, acc1, 0, 0, 0);    \
      acc0 = __builtin_amdgcn_mfma_f32_16x16x32_bf16(al, b0h, acc0, 0, 0, 0);    \
      acc1 = __builtin_amdgcn_mfma_f32_16x16x32_bf16(al, b1h, acc1, 0, 0, 0);    \
    }                                                                            \
    const float bias0 = (BPTR)[nc0 + (l & 15)];                                  \
    const float bias1 = (BPTR)[nc0 + 16 + (l & 15)];                             \
    EPI                                                                          \
  } while (0)

#define EPI_HIDDEN(DH, DL, DSTR)                                                 \
  {                                                                              \
    _Pragma("unroll")                                                            \
    for (int reg = 0; reg < 4; ++reg) {                                          \
      const int row = drow + reg;                                                \
      float v0 = fmaxf(acc0[reg] + bias0, 0.f);                                  \
      float v1 = fmaxf(acc1[reg] + bias1, 0.f);                                  \
      unsigned short h0 = f2bf(v0), h1v = f2bf(v1);                              \
      (DH)[row * (DSTR) + nc0 + (l & 15)] = h0;                                  \
      (DL)[row * (DSTR) + nc0 + (l & 15)] = f2bf(v0 - bf2f(h0));                 \
      (DH)[row * (DSTR) + nc0 + 16 + (l & 15)] = h1v;                            \
      (DL)[row * (DSTR) + nc0 + 16 + (l & 15)] = f2bf(v1 - bf2f(h1v));           \
    }                                                                            \
  }

  // ---- layer 2: K=256 ----
  MFMA_LAYER(8, 0, &s_h1hi[0][0], &s_h1lo[0][0], HS1, b2,
             EPI_HIDDEN(&s_h2hi[0][0], &s_h2lo[0][0], HS2));
  __syncthreads();

  // ---- layer 3: K=128 -> overwrite s_h1 ----
  MFMA_LAYER(4, 8, &s_h2hi[0][0], &s_h2lo[0][0], HS2, b3,
             EPI_HIDDEN(&s_h1hi[0][0], &s_h1lo[0][0], HS1));
  __syncthreads();

  // ---- layer 4: K=128, scatter-store via perm ----
  MFMA_LAYER(4, 12, &s_h1hi[0][0], &s_h1lo[0][0], HS1, b4, {
    _Pragma("unroll")
    for (int reg = 0; reg < 4; ++reg) {
      const unsigned int g = s_g[drow + reg];
      if (g != INVALID_IDX) {
        out[(size_t)g * DF + nc0 + (l & 15)] = acc0[reg] + bias0;
        out[(size_t)g * DF + nc0 + 16 + (l & 15)] = acc1[reg] + bias1;
      }
    }
  });
}

// ---------------- fp32 fallback path kernels ----------------
__global__ __launch_bounds__(256) void precompute_tables(
    const float* __restrict__ aa_emb, const float* __restrict__ chain_emb,
    const float* __restrict__ W1, const float* __restrict__ b1,
    float* __restrict__ tabAA, float* __restrict__ tabCH) {
  const int i = threadIdx.x;
  const int b = blockIdx.x;
  if (b < N_AA) {
    const float* e = aa_emb + b * DF;
    float acc = 0.f;
#pragma unroll 8
    for (int k = 0; k < DF; ++k) acc = fmaf(e[k], W1[k * H1DIM + i], acc);
    tabAA[b * H1DIM + i] = acc;
  } else {
    const int c = b - N_AA;
    const float* e = chain_emb + c * DF;
    float acc = b1[i];
#pragma unroll 8
    for (int k = 0; k < DF; ++k)
      acc = fmaf(e[k], W1[(OFF_CHAIN + k) * H1DIM + i], acc);
    tabCH[c * H1DIM + i] = acc;
  }
}

__global__ __launch_bounds__(512, 4) void residue_embed_fallback(
    const int* __restrict__ seq_idx, const float* __restrict__ xyz,
    const float* __restrict__ orient, const float* __restrict__ dihedrals,
    const int* __restrict__ chain_idx, const float* __restrict__ amask,
    const float* __restrict__ W1, const float* __restrict__ W2,
    const float* __restrict__ b2, const float* __restrict__ W3,
    const float* __restrict__ b3, const float* __restrict__ W4,
    const float* __restrict__ b4, const float* __restrict__ tabAA,
    const float* __restrict__ tabCH, float* __restrict__ out) {
  __shared__ float s_h1[T][260];
  __shared__ float s_buf2[T][132];
  __shared__ float s_w[32 * DF];
  __shared__ int s_t[T];
  __shared__ int s_c[T];

  const int tid = threadIdx.x;
  const int base = blockIdx.x * T;

  if (tid < T) {
    s_t[tid] = seq_idx[base + tid];
    s_c[tid] = chain_idx[base + tid];
  }
  for (int idx = tid; idx < T * 45; idx += 512) {
    const int r = idx / 45, k = idx % 45;
    const int a = k / 3, i = k % 3;
    const int g = base + r;
    const float* X = xyz + g * 45;
    const float* R = orient + g * 9;
    const float m = amask[g * NATOM + a];
    float v = 0.f;
#pragma unroll
    for (int j = 0; j < 3; ++j)
      v = fmaf(R[j * 3 + i], X[a * 3 + j] - X[3 + j], v);
    s_buf2[r][k] = v * m;
  }
  for (int idx = tid; idx < T * 39; idx += 512) {
    const int r = idx / 39, k = idx % 39;
    const int d = k / 13, m = k % 13;
    const float x = dihedrals[(base + r) * 3 + d];
    float v;
    if (m == 0) v = x;
    else if (m <= 6) v = sinf(c_freq[m - 1] * x);
    else v = cosf(c_freq[m - 7] * x);
    s_buf2[r][DIH0 + k] = v;
  }
  __syncthreads();
  {
    const int i0 = (tid & 63) * 4;
    const int r0 = (tid >> 6) * 4;
    float4 acc[4];
#pragma unroll
    for (int rr = 0; rr < 4; ++rr) {
      const int t = s_t[r0 + rr], c = s_c[r0 + rr];
      const float4 a = *(const float4*)(tabAA + t * H1DIM + i0);
      const float4 b = *(const float4*)(tabCH + c * H1DIM + i0);
      acc[rr].x = a.x + b.x; acc[rr].y = a.y + b.y;
      acc[rr].z = a.z + b.z; acc[rr].w = a.w + b.w;
    }
#pragma unroll 3
    for (int k = 0; k < 39; ++k) {
      const float4 wv = *(const float4*)(W1 + (OFF_DIH + k) * H1DIM + i0);
#pragma unroll
      for (int rr = 0; rr < 4; ++rr) {
        FMA4(acc[rr], s_buf2[r0 + rr][DIH0 + k], wv);
      }
    }
    const float* wp[4];
#pragma unroll
    for (int rr = 0; rr < 4; ++rr)
      wp[rr] = W1 + (OFF_COORD + s_t[r0 + rr] * 45) * H1DIM + i0;
    for (int k = 0; k < 45; ++k) {
#pragma unroll
      for (int rr = 0; rr < 4; ++rr) {
        const float4 wv = *(const float4*)(wp[rr] + k * H1DIM);
        FMA4(acc[rr], s_buf2[r0 + rr][k], wv);
      }
    }
#pragma unroll
    for (int rr = 0; rr < 4; ++rr) {
      float4 v;
      v.x = fmaxf(acc[rr].x, 0.f); v.y = fmaxf(acc[rr].y, 0.f);
      v.z = fmaxf(acc[rr].z, 0.f); v.w = fmaxf(acc[rr].w, 0.f);
      *(float4*)(&s_h1[r0 + rr][i0]) = v;
    }
  }
  const int j0 = (tid & 31) * 4;
  const int r2 = (tid >> 5) * 2;
#define FB_LAYER(NCH, WSRC, SRC, BPTR, STORE)                               \
  do {                                                                      \
    const float4 bb = *(const float4*)((BPTR) + j0);                        \
    float4 acc0 = bb, acc1 = bb;                                            \
    for (int c = 0; c < (NCH); ++c) {                                       \
      __syncthreads();                                                      \
      {                                                                     \
        const float* src = (WSRC) + c * 32 * DF;                            \
        const int idx = tid * 8;                                            \
        *(float4*)(&s_w[idx]) = *(const float4*)(src + idx);                \
        *(float4*)(&s_w[idx + 4]) = *(const float4*)(src + idx + 4);        \
      }                                                                     \
      __syncthreads();                                                      \
      const int kb2 = c * 32;                                               \
      _Pragma("unroll")                                                     \
      for (int kk = 0; kk < 32; kk += 4) {                                  \
        const float4 a0 = *(const float4*)(&(SRC)[r2][kb2 + kk]);           \
        const float4 a1 = *(const float4*)(&(SRC)[r2 + 1][kb2 + kk]);       \
        const float4 w0 = *(const float4*)(&s_w[(kk + 0) * DF + j0]);       \
        const float4 w1 = *(const float4*)(&s_w[(kk + 1) * DF + j0]);       \
        const float4 w2 = *(const float4*)(&s_w[(kk + 2) * DF + j0]);       \
        const float4 w3 = *(const float4*)(&s_w[(kk + 3) * DF + j0]);       \
        FMA4(acc0, a0.x, w0); FMA4(acc1, a1.x, w0);                         \
        FMA4(acc0, a0.y, w1); FMA4(acc1, a1.y, w1);                         \
        FMA4(acc0, a0.z, w2); FMA4(acc1, a1.z, w2);                         \
        FMA4(acc0, a0.w, w3); FMA4(acc1, a1.w, w3);                         \
      }                                                                     \
    }                                                                       \
    STORE                                                                   \
  } while (0)
#define RELU_STORE(DST)                                                     \
  {                                                                         \
    float4 v0, v1;                                                          \
    v0.x = fmaxf(acc0.x, 0.f); v0.y = fmaxf(acc0.y, 0.f);                   \
    v0.z = fmaxf(acc0.z, 0.f); v0.w = fmaxf(acc0.w, 0.f);                   \
    v1.x = fmaxf(acc1.x, 0.f); v1.y = fmaxf(acc1.y, 0.f);                   \
    v1.z = fmaxf(acc1.z, 0.f); v1.w = fmaxf(acc1.w, 0.f);                   \
    *(float4*)(&(DST)[r2][j0]) = v0;                                        \
    *(float4*)(&(DST)[r2 + 1][j0]) = v1;                                    \
  }
  FB_LAYER(8, W2, s_h1, b2, RELU_STORE(s_buf2));
  FB_LAYER(4, W3, s_buf2, b3, RELU_STORE(s_h1));
  FB_LAYER(4, W4, s_h1, b4, {
    *(float4*)(out + (size_t)(base + r2) * DF + j0) = acc0;
    *(float4*)(out + (size_t)(base + r2 + 1) * DF + j0) = acc1;
  });
}

extern "C" void kernel_launch(void* const* d_in, const int* in_sizes, int n_in,
                              void* d_out, int out_size, void* d_ws, size_t ws_size,
                              hipStream_t stream) {
  const int* seq = (const int*)d_in[0];
  const float* xyz = (const float*)d_in[1];
  const float* orient = (const float*)d_in[2];
  const float* dihedrals = (const float*)d_in[3];
  const int* chain = (const int*)d_in[4];
  const float* amask = (const float*)d_in[5];
  const float* aa_emb = (const float*)d_in[6];
  const float* chain_emb = (const float*)d_in[7];
  const float* W1 = (const float*)d_in[8];
  const float* b1 = (const float*)d_in[9];
  const float* W2 = (const float*)d_in[10];
  const float* b2 = (const float*)d_in[11];
  const float* W3 = (const float*)d_in[12];
  const float* b3 = (const float*)d_in[13];
  const float* W4 = (const float*)d_in[14];
  const float* b4 = (const float*)d_in[15];
  float* out = (float*)d_out;
  const int n_res = in_sizes[0];  // B*L = 32768

  // ---- ws layout ----
  char* wsp = (char*)d_ws;
  const size_t o_tabAA = 0;
  const size_t o_tabCH = o_tabAA + (size_t)N_AA * H1DIM * 4;
  const size_t o_wfhi = (o_tabCH + (size_t)10 * H1DIM * 4 + 255) & ~255ull;
  const size_t o_wflo = o_wfhi + (size_t)NFRAG_CH * 8 * 512 * 2;
  const size_t o_wl1 = o_wflo + (size_t)NFRAG_CH * 8 * 512 * 2;
  const size_t wl1_bytes = (size_t)N_AA * 3 * 16 * 512 * 2;
  const size_t o_cnt = (o_wl1 + wl1_bytes + 255) & ~255ull;  // counts[21]+fill[21]
  const size_t o_perm = (o_cnt + 2 * N_AA * 4 + 255) & ~255ull;
  const int npad_max = n_res + N_AA * 15;
  const int nblkB = (npad_max + T - 1) / T;
  const int cap = nblkB * T;
  const size_t perm_bytes = (size_t)cap * 4;
  const size_t need = o_perm + perm_bytes;

  float* tabAA = (float*)(wsp + o_tabAA);
  float* tabCH = (float*)(wsp + o_tabCH);

  if (ws_size >= need) {
    unsigned short* wf_hi = (unsigned short*)(wsp + o_wfhi);
    unsigned short* wf_lo = (unsigned short*)(wsp + o_wflo);
    unsigned short* wl1 = (unsigned short*)(wsp + o_wl1);
    int* counts = (int*)(wsp + o_cnt);
    int* fill = counts + N_AA;
    unsigned int* perm = (unsigned int*)(wsp + o_perm);

    hipMemsetAsync(counts, 0, 2 * N_AA * 4, stream);

    const int nprep = PR_TAB + PR_WF + PR_WL + PR_HIST;
    hipLaunchKernelGGL(prep_all, dim3(nprep), dim3(256), 0, stream, aa_emb,
                       chain_emb, W1, b1, W2, W3, W4, seq, n_res, tabAA, tabCH,
                       wf_hi, wf_lo, wl1, counts);

    const int nblkH = (n_res + 255) / 256;
    hipLaunchKernelGGL(scatter_pad, dim3(nblkH + N_AA + 1), dim3(256), 0,
                       stream, seq, n_res, cap, counts, fill, perm);

    hipLaunchKernelGGL(residue_embed_sorted, dim3(nblkB), dim3(512), 0, stream,
                       xyz, orient, dihedrals, chain, amask, b2, b3, b4, tabAA,
                       tabCH, wl1, wf_hi, wf_lo, counts, perm, out);
  } else {
    hipLaunchKernelGGL(precompute_tables, dim3(N_AA + 10), dim3(256), 0, stream,
                       aa_emb, chain_emb, W1, b1, tabAA, tabCH);
    const int nblk = n_res / T;
    hipLaunchKernelGGL(residue_embed_fallback, dim3(nblk), dim3(512), 0, stream,
                       seq, xyz, orient, dihedrals, chain, amask, W1, W2, b2,
                       W3, b3, W4, b4, tabAA, tabCH, out);
  }
}